// Round 1
// baseline (1592.816 us; speedup 1.0000x reference)
//
#include <hip/hip_runtime.h>
#include <cmath>

constexpr int NN  = 50000;          // nodes
constexpr int EE  = 800000;         // raw edges
constexpr int E2C = EE + NN;        // edges incl. self loops = 850000
constexpr int DIM = 128;            // D = HEADS*C = 128

// ---------------------------------------------------------------------------
// GEMM (in[N,128] @ W[128,COLS]) fused with per-node attention coefficients:
//   asrc[n,h] = sum_c h[n,h,c]*a_s[h,c],  adst likewise.
// COLS=128 -> 1 node/block (layers 1,2).  COLS=32 -> 4 nodes/block (layer 3).
// ---------------------------------------------------------------------------
template<int COLS>
__global__ __launch_bounds__(128) void gemm_alpha(
    const float* __restrict__ in, const float* __restrict__ W,
    const float* __restrict__ a_s, const float* __restrict__ a_d,
    float* __restrict__ hout, float* __restrict__ asrc, float* __restrict__ adst)
{
    constexpr int NPB = DIM / COLS;           // nodes per block
    __shared__ float xs[NPB * DIM];
    const int tid = threadIdx.x;
    const int nodeBase = blockIdx.x * NPB;
    #pragma unroll
    for (int i = 0; i < NPB; ++i)
        xs[tid + i * 128] = in[(long long)nodeBase * DIM + tid + i * 128];
    __syncthreads();

    const int sub  = tid / COLS;
    const int c    = tid % COLS;
    const int node = nodeBase + sub;
    const float* xrow = &xs[sub * DIM];

    float acc = 0.f;
    #pragma unroll 8
    for (int k = 0; k < DIM; ++k)
        acc = fmaf(xrow[k], W[k * COLS + c], acc);

    hout[(long long)node * COLS + c] = acc;

    float ps = acc * a_s[c];
    float pd = acc * a_d[c];
    #pragma unroll
    for (int off = 16; off > 0; off >>= 1) {
        ps += __shfl_down(ps, off, 32);       // reduce within 32-lane head group
        pd += __shfl_down(pd, off, 32);
    }
    if ((tid & 31) == 0) {
        constexpr int NH = COLS / 32;         // heads (4 or 1)
        asrc[node * NH + (c >> 5)] = ps;
        adst[node * NH + (c >> 5)] = pd;
    }
}

// ---------------------------------------------------------------------------
// Pass 1 over edges: softmax denominators (no max-shift: logits are O(1)).
// ---------------------------------------------------------------------------
template<int NH>
__global__ void edge_den(const int* __restrict__ ei,
                         const float* __restrict__ asrc, const float* __restrict__ adst,
                         float* __restrict__ den)
{
    int e = blockIdx.x * 256 + threadIdx.x;
    if (e >= E2C) return;
    int s, d;
    if (e < EE) { s = ei[e]; d = ei[EE + e]; } else { s = d = e - EE; }
    #pragma unroll
    for (int h = 0; h < NH; ++h) {
        float l = asrc[s * NH + h] + adst[d * NH + h];
        l = l > 0.f ? l : 0.2f * l;          // leaky_relu(0.2)
        atomicAdd(&den[d * NH + h], __builtin_expf(l));
    }
}

// ---------------------------------------------------------------------------
// Pass 2 over edges: out[dst] += (exp(logit)/den[dst]) * h[src].
// One thread per (edge, channel); logit recomputed (uniform per 32 lanes).
// ---------------------------------------------------------------------------
template<int COLS>
__global__ void edge_aggr(const int* __restrict__ ei,
                          const float* __restrict__ hin,
                          const float* __restrict__ asrc, const float* __restrict__ adst,
                          const float* __restrict__ den, float* __restrict__ out)
{
    constexpr int NH = COLS / 32;
    int idx = blockIdx.x * 256 + threadIdx.x;
    int e = idx / COLS;
    int c = idx % COLS;
    if (e >= E2C) return;
    int s, d;
    if (e < EE) { s = ei[e]; d = ei[EE + e]; } else { s = d = e - EE; }
    int head = c >> 5;
    float l = asrc[s * NH + head] + adst[d * NH + head];
    l = l > 0.f ? l : 0.2f * l;
    float w = __builtin_expf(l) / (den[d * NH + head] + 1e-16f);
    atomicAdd(&out[(long long)d * COLS + c], hin[(long long)s * COLS + c] * w);
}

// ---------------------------------------------------------------------------
// Epilogue: bias add (+ ELU for layers 1,2), in place.
// ---------------------------------------------------------------------------
template<bool DO_ELU, int COLS>
__global__ void epilogue(float* __restrict__ io, const float* __restrict__ b)
{
    int i = blockIdx.x * 256 + threadIdx.x;
    if (i >= NN * COLS) return;
    float v = io[i] + b[i & (COLS - 1)];
    if (DO_ELU) v = v > 0.f ? v : expm1f(v);
    io[i] = v;
}

// ---------------------------------------------------------------------------
extern "C" void kernel_launch(void* const* d_in, const int* in_sizes, int n_in,
                              void* d_out, int out_size, void* d_ws, size_t ws_size,
                              hipStream_t stream)
{
    const float* x   = (const float*)d_in[0];
    const int*   ei  = (const int*)  d_in[1];
    const float* W1  = (const float*)d_in[2];
    const float* as1 = (const float*)d_in[3];
    const float* ad1 = (const float*)d_in[4];
    const float* b1  = (const float*)d_in[5];
    const float* W2  = (const float*)d_in[6];
    const float* as2 = (const float*)d_in[7];
    const float* ad2 = (const float*)d_in[8];
    const float* b2  = (const float*)d_in[9];
    const float* W3  = (const float*)d_in[10];
    const float* as3 = (const float*)d_in[11];
    const float* ad3 = (const float*)d_in[12];
    const float* b3  = (const float*)d_in[13];
    float* out = (float*)d_out;

    // workspace layout (floats)
    float* ws   = (float*)d_ws;
    float* H    = ws;                          // N*128
    float* O    = H    + (size_t)NN * 128;     // N*128
    float* ASRC = O    + (size_t)NN * 128;     // N*4
    float* ADST = ASRC + (size_t)NN * 4;       // N*4
    float* DEN  = ADST + (size_t)NN * 4;       // N*4

    const int gEdge   = (E2C + 255) / 256;           // 3321
    const int gAggr128 = (E2C * 128) / 256;          // 425000 (exact)
    const int gAggr32  = (E2C * 32) / 256;           // 106250 (exact)
    const int gEpi128  = (NN * 128) / 256;           // 25000
    const int gEpi32   = (NN * 32) / 256;            // 6250

    // ---- layer 1 (128 -> 4x32 concat) ----
    gemm_alpha<128><<<NN, 128, 0, stream>>>(x, W1, as1, ad1, H, ASRC, ADST);
    hipMemsetAsync(DEN, 0, (size_t)NN * 4 * sizeof(float), stream);
    hipMemsetAsync(O,   0, (size_t)NN * 128 * sizeof(float), stream);
    edge_den<4><<<gEdge, 256, 0, stream>>>(ei, ASRC, ADST, DEN);
    edge_aggr<128><<<gAggr128, 256, 0, stream>>>(ei, H, ASRC, ADST, DEN, O);
    epilogue<true, 128><<<gEpi128, 256, 0, stream>>>(O, b1);

    // ---- layer 2 (128 -> 4x32 concat) ----
    gemm_alpha<128><<<NN, 128, 0, stream>>>(O, W2, as2, ad2, H, ASRC, ADST);
    hipMemsetAsync(DEN, 0, (size_t)NN * 4 * sizeof(float), stream);
    // O is consumed by the GEMM above before this memset runs (stream order)
    hipMemsetAsync(O,   0, (size_t)NN * 128 * sizeof(float), stream);
    edge_den<4><<<gEdge, 256, 0, stream>>>(ei, ASRC, ADST, DEN);
    edge_aggr<128><<<gAggr128, 256, 0, stream>>>(ei, H, ASRC, ADST, DEN, O);
    epilogue<true, 128><<<gEpi128, 256, 0, stream>>>(O, b2);

    // ---- layer 3 (128 -> 32, 1 head, no concat) ----
    gemm_alpha<32><<<NN / 4, 128, 0, stream>>>(O, W3, as3, ad3, H, ASRC, ADST);
    hipMemsetAsync(DEN, 0, (size_t)NN * sizeof(float), stream);
    hipMemsetAsync(out, 0, (size_t)NN * 32 * sizeof(float), stream);
    edge_den<1><<<gEdge, 256, 0, stream>>>(ei, ASRC, ADST, DEN);
    edge_aggr<32><<<gAggr32, 256, 0, stream>>>(ei, H, ASRC, ADST, DEN, out);
    epilogue<false, 32><<<gEpi32, 256, 0, stream>>>(out, b3);
}

// Round 2
// 811.018 us; speedup vs baseline: 1.9640x; 1.9640x over previous
//
#include <hip/hip_runtime.h>
#include <cmath>

constexpr int NN  = 50000;          // nodes
constexpr int EE  = 800000;         // raw edges
constexpr int E2C = EE + NN;        // edges incl. self loops = 850000
constexpr int DIM = 128;            // D = HEADS*C = 128
constexpr int SCAN_B = (NN + 255) / 256;   // 196 scan blocks

// ---------------------------------------------------------------------------
// GEMM (in[N,128] @ W[128,COLS]) fused with per-node attention coefficients.
// ---------------------------------------------------------------------------
template<int COLS>
__global__ __launch_bounds__(128) void gemm_alpha(
    const float* __restrict__ in, const float* __restrict__ W,
    const float* __restrict__ a_s, const float* __restrict__ a_d,
    float* __restrict__ hout, float* __restrict__ asrc, float* __restrict__ adst)
{
    constexpr int NPB = DIM / COLS;           // nodes per block
    __shared__ float xs[NPB * DIM];
    const int tid = threadIdx.x;
    const int nodeBase = blockIdx.x * NPB;
    #pragma unroll
    for (int i = 0; i < NPB; ++i)
        xs[tid + i * 128] = in[(long long)nodeBase * DIM + tid + i * 128];
    __syncthreads();

    const int sub  = tid / COLS;
    const int c    = tid % COLS;
    const int node = nodeBase + sub;
    const float* xrow = &xs[sub * DIM];

    float acc = 0.f;
    #pragma unroll 8
    for (int k = 0; k < DIM; ++k)
        acc = fmaf(xrow[k], W[k * COLS + c], acc);

    hout[(long long)node * COLS + c] = acc;

    float ps = acc * a_s[c];
    float pd = acc * a_d[c];
    #pragma unroll
    for (int off = 16; off > 0; off >>= 1) {
        ps += __shfl_down(ps, off, 32);       // reduce within 32-lane head group
        pd += __shfl_down(pd, off, 32);
    }
    if ((tid & 31) == 0) {
        constexpr int NH = COLS / 32;         // heads (4 or 1)
        asrc[node * NH + (c >> 5)] = ps;
        adst[node * NH + (c >> 5)] = pd;
    }
}

// ---------------------------------------------------------------------------
// CSR construction by dst:  histogram -> exclusive scan -> scatter.
// ---------------------------------------------------------------------------
__global__ void hist_kernel(const int* __restrict__ ei, int* __restrict__ counts)
{
    int e = blockIdx.x * 256 + threadIdx.x;
    if (e >= E2C) return;
    int d = (e < EE) ? ei[EE + e] : e - EE;
    atomicAdd(&counts[d], 1);
}

__global__ void scan1(const int* __restrict__ counts, int* __restrict__ rowptr,
                      int* __restrict__ partials)
{
    __shared__ int tmp[256];
    int i = blockIdx.x * 256 + threadIdx.x;
    int v = (i < NN) ? counts[i] : 0;
    tmp[threadIdx.x] = v;
    __syncthreads();
    for (int off = 1; off < 256; off <<= 1) {
        int t = (threadIdx.x >= off) ? tmp[threadIdx.x - off] : 0;
        __syncthreads();
        tmp[threadIdx.x] += t;
        __syncthreads();
    }
    if (i < NN) rowptr[i] = tmp[threadIdx.x] - v;   // exclusive within block
    if (threadIdx.x == 255) partials[blockIdx.x] = tmp[255];
}

__global__ void scan2(int* __restrict__ partials)    // single block of 256
{
    __shared__ int tmp[256];
    int v = (threadIdx.x < SCAN_B) ? partials[threadIdx.x] : 0;
    tmp[threadIdx.x] = v;
    __syncthreads();
    for (int off = 1; off < 256; off <<= 1) {
        int t = (threadIdx.x >= off) ? tmp[threadIdx.x - off] : 0;
        __syncthreads();
        tmp[threadIdx.x] += t;
        __syncthreads();
    }
    if (threadIdx.x < SCAN_B) partials[threadIdx.x] = tmp[threadIdx.x] - v;
}

__global__ void scan3(int* __restrict__ rowptr, int* __restrict__ cursor,
                      const int* __restrict__ partials)
{
    int i = blockIdx.x * 256 + threadIdx.x;
    if (i < NN) {
        int v = rowptr[i] + partials[blockIdx.x];
        rowptr[i] = v;
        cursor[i] = v;
    }
    if (i == 0) rowptr[NN] = E2C;
}

__global__ void scatter_kernel(const int* __restrict__ ei, int* __restrict__ cursor,
                               int* __restrict__ sorted_src)
{
    int e = blockIdx.x * 256 + threadIdx.x;
    if (e >= E2C) return;
    int s, d;
    if (e < EE) { s = ei[e]; d = ei[EE + e]; } else { s = d = e - EE; }
    int pos = atomicAdd(&cursor[d], 1);
    sorted_src[pos] = s;
}

// ---------------------------------------------------------------------------
// CSR gather aggregation, fused softmax + bias (+ ELU). COLS threads per dst
// node accumulate num (per-channel) and den (softmax denom) in registers.
// ---------------------------------------------------------------------------
template<int COLS, int NH, bool DO_ELU>
__global__ __launch_bounds__(256) void aggr_csr(
    const int* __restrict__ rowptr, const int* __restrict__ sorted_src,
    const float* __restrict__ hin,
    const float* __restrict__ asrc, const float* __restrict__ adst,
    const float* __restrict__ bias, float* __restrict__ out)
{
    int t = blockIdx.x * 256 + threadIdx.x;
    int d = t / COLS;
    int c = t % COLS;
    if (d >= NN) return;
    const int head = c >> 5;                  // 0..NH-1
    const float ad = adst[d * NH + head];
    const int beg = rowptr[d], end = rowptr[d + 1];

    float num = 0.f, den = 0.f;
    for (int i = beg; i < end; ++i) {
        int s = sorted_src[i];
        float l = asrc[s * NH + head] + ad;
        l = l > 0.f ? l : 0.2f * l;           // leaky_relu(0.2)
        float w = __builtin_expf(l);
        den += w;
        num = fmaf(w, hin[(long long)s * COLS + c], num);
    }
    float v = num / (den + 1e-16f) + bias[c];
    if (DO_ELU) v = v > 0.f ? v : expm1f(v);
    out[(long long)d * COLS + c] = v;
}

// ---------------------------------------------------------------------------
extern "C" void kernel_launch(void* const* d_in, const int* in_sizes, int n_in,
                              void* d_out, int out_size, void* d_ws, size_t ws_size,
                              hipStream_t stream)
{
    const float* x   = (const float*)d_in[0];
    const int*   ei  = (const int*)  d_in[1];
    const float* W1  = (const float*)d_in[2];
    const float* as1 = (const float*)d_in[3];
    const float* ad1 = (const float*)d_in[4];
    const float* b1  = (const float*)d_in[5];
    const float* W2  = (const float*)d_in[6];
    const float* as2 = (const float*)d_in[7];
    const float* ad2 = (const float*)d_in[8];
    const float* b2  = (const float*)d_in[9];
    const float* W3  = (const float*)d_in[10];
    const float* as3 = (const float*)d_in[11];
    const float* ad3 = (const float*)d_in[12];
    const float* b3  = (const float*)d_in[13];
    float* out = (float*)d_out;

    // workspace layout
    float* ws   = (float*)d_ws;
    float* H    = ws;                          // N*128 f
    float* O    = H    + (size_t)NN * 128;     // N*128 f
    float* ASRC = O    + (size_t)NN * 128;     // N*4 f
    float* ADST = ASRC + (size_t)NN * 4;       // N*4 f
    int* rowptr = (int*)(ADST + (size_t)NN * 4);          // NN+1
    int* cursor = rowptr + (NN + 1);                      // NN (also histogram counts)
    int* sorted = cursor + NN;                            // E2C
    int* partials = sorted + E2C;                         // SCAN_B

    const int gEdge = (E2C + 255) / 256;             // 3321
    const int gAggr128 = (NN * 128) / 256;           // 25000
    const int gAggr32  = (NN * 32) / 256;            // 6250

    // ---- build CSR (dst-sorted) once; reused by all 3 layers ----
    hipMemsetAsync(cursor, 0, (size_t)NN * sizeof(int), stream);
    hist_kernel<<<gEdge, 256, 0, stream>>>(ei, cursor);
    scan1<<<SCAN_B, 256, 0, stream>>>(cursor, rowptr, partials);
    scan2<<<1, 256, 0, stream>>>(partials);
    scan3<<<SCAN_B, 256, 0, stream>>>(rowptr, cursor, partials);
    scatter_kernel<<<gEdge, 256, 0, stream>>>(ei, cursor, sorted);

    // ---- layer 1 (128 -> 4x32 concat, ELU) ----
    gemm_alpha<128><<<NN, 128, 0, stream>>>(x, W1, as1, ad1, H, ASRC, ADST);
    aggr_csr<128, 4, true><<<gAggr128, 256, 0, stream>>>(rowptr, sorted, H, ASRC, ADST, b1, O);

    // ---- layer 2 (128 -> 4x32 concat, ELU) ----
    gemm_alpha<128><<<NN, 128, 0, stream>>>(O, W2, as2, ad2, H, ASRC, ADST);
    aggr_csr<128, 4, true><<<gAggr128, 256, 0, stream>>>(rowptr, sorted, H, ASRC, ADST, b2, O);

    // ---- layer 3 (128 -> 32, 1 head, no concat) ----
    gemm_alpha<32><<<NN / 4, 128, 0, stream>>>(O, W3, as3, ad3, H, ASRC, ADST);
    aggr_csr<32, 1, false><<<gAggr32, 256, 0, stream>>>(rowptr, sorted, H, ASRC, ADST, b3, out);
}

// Round 3
// 473.955 us; speedup vs baseline: 3.3607x; 1.7112x over previous
//
#include <hip/hip_runtime.h>
#include <cmath>

constexpr int NN  = 50000;          // nodes
constexpr int EE  = 800000;         // raw edges
constexpr int E2C = EE + NN;        // edges incl. self loops = 850000
constexpr int DIM = 128;            // D = HEADS*C = 128
constexpr int SCAN_B = (NN + 255) / 256;   // 196 scan blocks

// ---------------------------------------------------------------------------
// Layer-1/2 GEMM: in[N,128] @ W[128,128], 8 nodes per 128-thread block.
// x is addressed uniformly (no threadIdx) -> compiler emits scalar loads,
// W read once per k per lane -> W L2 traffic = 6250 blocks * 64KB = 400 MB.
// Fused per-node attention coefficients via 32-lane shuffle reduction.
// ---------------------------------------------------------------------------
constexpr int NPT = 8;
__global__ __launch_bounds__(128) void gemm128(
    const float* __restrict__ in, const float* __restrict__ W,
    const float* __restrict__ a_s, const float* __restrict__ a_d,
    float* __restrict__ hout, float* __restrict__ asrc, float* __restrict__ adst)
{
    const int c  = threadIdx.x;
    const int n0 = blockIdx.x * NPT;
    const float* xblk = in + (long long)n0 * DIM;

    float acc[NPT] = {};
    #pragma unroll 4
    for (int k = 0; k < DIM; ++k) {
        float w = W[k * DIM + c];
        #pragma unroll
        for (int j = 0; j < NPT; ++j)
            acc[j] = fmaf(xblk[j * DIM + k], w, acc[j]);   // x: SGPR operand
    }

    const float asc = a_s[c];
    const float adc = a_d[c];
    const int head = c >> 5;
    #pragma unroll
    for (int j = 0; j < NPT; ++j) {
        hout[(long long)(n0 + j) * DIM + c] = acc[j];
        float ps = acc[j] * asc;
        float pd = acc[j] * adc;
        #pragma unroll
        for (int off = 16; off > 0; off >>= 1) {
            ps += __shfl_down(ps, off, 32);
            pd += __shfl_down(pd, off, 32);
        }
        if ((c & 31) == 0) {
            asrc[(n0 + j) * 4 + head] = ps;
            adst[(n0 + j) * 4 + head] = pd;
        }
    }
}

// ---------------------------------------------------------------------------
// Layer-3 GEMM (128 -> 32): 4 nodes per 128-thread block (W3 is only 16 KB).
// ---------------------------------------------------------------------------
__global__ __launch_bounds__(128) void gemm32(
    const float* __restrict__ in, const float* __restrict__ W,
    const float* __restrict__ a_s, const float* __restrict__ a_d,
    float* __restrict__ hout, float* __restrict__ asrc, float* __restrict__ adst)
{
    __shared__ float xs[4 * DIM];
    const int tid = threadIdx.x;
    const int nodeBase = blockIdx.x * 4;
    #pragma unroll
    for (int i = 0; i < 4; ++i)
        xs[tid + i * 128] = in[(long long)nodeBase * DIM + tid + i * 128];
    __syncthreads();

    const int sub  = tid / 32;
    const int c    = tid % 32;
    const int node = nodeBase + sub;
    const float* xrow = &xs[sub * DIM];

    float acc = 0.f;
    #pragma unroll 8
    for (int k = 0; k < DIM; ++k)
        acc = fmaf(xrow[k], W[k * 32 + c], acc);

    hout[(long long)node * 32 + c] = acc;

    float ps = acc * a_s[c];
    float pd = acc * a_d[c];
    #pragma unroll
    for (int off = 16; off > 0; off >>= 1) {
        ps += __shfl_down(ps, off, 32);
        pd += __shfl_down(pd, off, 32);
    }
    if (c == 0) {
        asrc[node] = ps;
        adst[node] = pd;
    }
}

// ---------------------------------------------------------------------------
// CSR construction by dst:  histogram -> exclusive scan -> scatter.
// ---------------------------------------------------------------------------
__global__ void hist_kernel(const int* __restrict__ ei, int* __restrict__ counts)
{
    int e = blockIdx.x * 256 + threadIdx.x;
    if (e >= E2C) return;
    int d = (e < EE) ? ei[EE + e] : e - EE;
    atomicAdd(&counts[d], 1);
}

__global__ void scan1(const int* __restrict__ counts, int* __restrict__ rowptr,
                      int* __restrict__ partials)
{
    __shared__ int tmp[256];
    int i = blockIdx.x * 256 + threadIdx.x;
    int v = (i < NN) ? counts[i] : 0;
    tmp[threadIdx.x] = v;
    __syncthreads();
    for (int off = 1; off < 256; off <<= 1) {
        int t = (threadIdx.x >= off) ? tmp[threadIdx.x - off] : 0;
        __syncthreads();
        tmp[threadIdx.x] += t;
        __syncthreads();
    }
    if (i < NN) rowptr[i] = tmp[threadIdx.x] - v;
    if (threadIdx.x == 255) partials[blockIdx.x] = tmp[255];
}

__global__ void scan2(int* __restrict__ partials)    // single block of 256
{
    __shared__ int tmp[256];
    int v = (threadIdx.x < SCAN_B) ? partials[threadIdx.x] : 0;
    tmp[threadIdx.x] = v;
    __syncthreads();
    for (int off = 1; off < 256; off <<= 1) {
        int t = (threadIdx.x >= off) ? tmp[threadIdx.x - off] : 0;
        __syncthreads();
        tmp[threadIdx.x] += t;
        __syncthreads();
    }
    if (threadIdx.x < SCAN_B) partials[threadIdx.x] = tmp[threadIdx.x] - v;
}

__global__ void scan3(int* __restrict__ rowptr, int* __restrict__ cursor,
                      const int* __restrict__ partials)
{
    int i = blockIdx.x * 256 + threadIdx.x;
    if (i < NN) {
        int v = rowptr[i] + partials[blockIdx.x];
        rowptr[i] = v;
        cursor[i] = v;
    }
    if (i == 0) rowptr[NN] = E2C;
}

__global__ void scatter_kernel(const int* __restrict__ ei, int* __restrict__ cursor,
                               int* __restrict__ sorted_src)
{
    int e = blockIdx.x * 256 + threadIdx.x;
    if (e >= E2C) return;
    int s, d;
    if (e < EE) { s = ei[e]; d = ei[EE + e]; } else { s = d = e - EE; }
    int pos = atomicAdd(&cursor[d], 1);
    sorted_src[pos] = s;
}

// ---------------------------------------------------------------------------
// CSR gather aggregation, float4 per thread + 4-edge batching (12 independent
// loads in flight per chunk). COLS/4 threads per dst node.
// ---------------------------------------------------------------------------
template<int COLS, int NH, bool DO_ELU>
__global__ __launch_bounds__(256) void aggr_csr4(
    const int* __restrict__ rowptr, const int* __restrict__ sorted_src,
    const float* __restrict__ hin,
    const float* __restrict__ asrc, const float* __restrict__ adst,
    const float* __restrict__ bias, float* __restrict__ out)
{
    constexpr int TPN = COLS / 4;             // threads per node: 32 or 8
    int t = blockIdx.x * 256 + threadIdx.x;
    int d = t / TPN;
    int lc = t % TPN;                         // owns channels 4*lc .. 4*lc+3
    if (d >= NN) return;
    const int head = (4 * lc) >> 5;           // 0..NH-1
    const float ad = adst[d * NH + head];
    const int beg = rowptr[d], end = rowptr[d + 1];

    float4 num = {0.f, 0.f, 0.f, 0.f};
    float den = 0.f;
    int i = beg;
    for (; i + 4 <= end; i += 4) {
        int s0 = sorted_src[i];
        int s1 = sorted_src[i + 1];
        int s2 = sorted_src[i + 2];
        int s3 = sorted_src[i + 3];
        float a0 = asrc[s0 * NH + head];
        float a1 = asrc[s1 * NH + head];
        float a2 = asrc[s2 * NH + head];
        float a3 = asrc[s3 * NH + head];
        float4 h0 = *(const float4*)&hin[(long long)s0 * COLS + 4 * lc];
        float4 h1 = *(const float4*)&hin[(long long)s1 * COLS + 4 * lc];
        float4 h2 = *(const float4*)&hin[(long long)s2 * COLS + 4 * lc];
        float4 h3 = *(const float4*)&hin[(long long)s3 * COLS + 4 * lc];
        float l0 = a0 + ad; l0 = l0 > 0.f ? l0 : 0.2f * l0;
        float l1 = a1 + ad; l1 = l1 > 0.f ? l1 : 0.2f * l1;
        float l2 = a2 + ad; l2 = l2 > 0.f ? l2 : 0.2f * l2;
        float l3 = a3 + ad; l3 = l3 > 0.f ? l3 : 0.2f * l3;
        float w0 = __builtin_expf(l0);
        float w1 = __builtin_expf(l1);
        float w2 = __builtin_expf(l2);
        float w3 = __builtin_expf(l3);
        den += (w0 + w1) + (w2 + w3);
        num.x = fmaf(w0, h0.x, num.x); num.y = fmaf(w0, h0.y, num.y);
        num.z = fmaf(w0, h0.z, num.z); num.w = fmaf(w0, h0.w, num.w);
        num.x = fmaf(w1, h1.x, num.x); num.y = fmaf(w1, h1.y, num.y);
        num.z = fmaf(w1, h1.z, num.z); num.w = fmaf(w1, h1.w, num.w);
        num.x = fmaf(w2, h2.x, num.x); num.y = fmaf(w2, h2.y, num.y);
        num.z = fmaf(w2, h2.z, num.z); num.w = fmaf(w2, h2.w, num.w);
        num.x = fmaf(w3, h3.x, num.x); num.y = fmaf(w3, h3.y, num.y);
        num.z = fmaf(w3, h3.z, num.z); num.w = fmaf(w3, h3.w, num.w);
    }
    for (; i < end; ++i) {
        int s = sorted_src[i];
        float a = asrc[s * NH + head];
        float4 h = *(const float4*)&hin[(long long)s * COLS + 4 * lc];
        float l = a + ad; l = l > 0.f ? l : 0.2f * l;
        float w = __builtin_expf(l);
        den += w;
        num.x = fmaf(w, h.x, num.x); num.y = fmaf(w, h.y, num.y);
        num.z = fmaf(w, h.z, num.z); num.w = fmaf(w, h.w, num.w);
    }

    float inv = 1.f / (den + 1e-16f);
    const float4 b4 = *(const float4*)&bias[4 * lc];
    float4 v;
    v.x = num.x * inv + b4.x;
    v.y = num.y * inv + b4.y;
    v.z = num.z * inv + b4.z;
    v.w = num.w * inv + b4.w;
    if (DO_ELU) {
        v.x = v.x > 0.f ? v.x : expm1f(v.x);
        v.y = v.y > 0.f ? v.y : expm1f(v.y);
        v.z = v.z > 0.f ? v.z : expm1f(v.z);
        v.w = v.w > 0.f ? v.w : expm1f(v.w);
    }
    *(float4*)&out[(long long)d * COLS + 4 * lc] = v;
}

// ---------------------------------------------------------------------------
extern "C" void kernel_launch(void* const* d_in, const int* in_sizes, int n_in,
                              void* d_out, int out_size, void* d_ws, size_t ws_size,
                              hipStream_t stream)
{
    const float* x   = (const float*)d_in[0];
    const int*   ei  = (const int*)  d_in[1];
    const float* W1  = (const float*)d_in[2];
    const float* as1 = (const float*)d_in[3];
    const float* ad1 = (const float*)d_in[4];
    const float* b1  = (const float*)d_in[5];
    const float* W2  = (const float*)d_in[6];
    const float* as2 = (const float*)d_in[7];
    const float* ad2 = (const float*)d_in[8];
    const float* b2  = (const float*)d_in[9];
    const float* W3  = (const float*)d_in[10];
    const float* as3 = (const float*)d_in[11];
    const float* ad3 = (const float*)d_in[12];
    const float* b3  = (const float*)d_in[13];
    float* out = (float*)d_out;

    // workspace layout
    float* ws   = (float*)d_ws;
    float* H    = ws;                          // N*128 f
    float* O    = H    + (size_t)NN * 128;     // N*128 f
    float* ASRC = O    + (size_t)NN * 128;     // N*4 f
    float* ADST = ASRC + (size_t)NN * 4;       // N*4 f
    int* rowptr = (int*)(ADST + (size_t)NN * 4);          // NN+1
    int* cursor = rowptr + (NN + 1);                      // NN (also histogram)
    int* sorted = cursor + NN;                            // E2C
    int* partials = sorted + E2C;                         // SCAN_B

    const int gEdge = (E2C + 255) / 256;                 // 3321
    const int gAggr128 = (NN * 32 + 255) / 256;          // 6250
    const int gAggr32  = (NN * 8 + 255) / 256;           // 1563

    // ---- build CSR (dst-sorted) once; reused by all 3 layers ----
    hipMemsetAsync(cursor, 0, (size_t)NN * sizeof(int), stream);
    hist_kernel<<<gEdge, 256, 0, stream>>>(ei, cursor);
    scan1<<<SCAN_B, 256, 0, stream>>>(cursor, rowptr, partials);
    scan2<<<1, 256, 0, stream>>>(partials);
    scan3<<<SCAN_B, 256, 0, stream>>>(rowptr, cursor, partials);
    scatter_kernel<<<gEdge, 256, 0, stream>>>(ei, cursor, sorted);

    // ---- layer 1 (128 -> 4x32 concat, ELU) ----
    gemm128<<<NN / NPT, 128, 0, stream>>>(x, W1, as1, ad1, H, ASRC, ADST);
    aggr_csr4<128, 4, true><<<gAggr128, 256, 0, stream>>>(rowptr, sorted, H, ASRC, ADST, b1, O);

    // ---- layer 2 (128 -> 4x32 concat, ELU) ----
    gemm128<<<NN / NPT, 128, 0, stream>>>(O, W2, as2, ad2, H, ASRC, ADST);
    aggr_csr4<128, 4, true><<<gAggr128, 256, 0, stream>>>(rowptr, sorted, H, ASRC, ADST, b2, O);

    // ---- layer 3 (128 -> 32, 1 head, no concat) ----
    gemm32<<<NN / 4, 128, 0, stream>>>(O, W3, as3, ad3, H, ASRC, ADST);
    aggr_csr4<32, 1, false><<<gAggr32, 256, 0, stream>>>(rowptr, sorted, H, ASRC, ADST, b3, out);
}

// Round 4
// 413.719 us; speedup vs baseline: 3.8500x; 1.1456x over previous
//
#include <hip/hip_runtime.h>
#include <cmath>

constexpr int NN  = 50000;          // nodes
constexpr int EE  = 800000;         // raw edges
constexpr int E2C = EE + NN;        // edges incl. self loops = 850000
constexpr int DIM = 128;            // input dim to every layer's GEMM
constexpr int SCAN_B = (NN + 255) / 256;   // 196 scan blocks

// ---------------------------------------------------------------------------
// LDS-tiled GEMM  in[N,128] @ W[128,COLS]  + fused attention coefficients.
// 256 threads; 4x4 register tile per thread (4 nodes x 4 cols).
// COLS=128: 32 nodes/block.  COLS=32: 128 nodes/block.  K-tile = 32.
// xs stored transposed (xs[k][n], stride TILE_N+4 -> 16B-aligned b128 reads).
// alpha: 8-lane shuffle reduction (col-groups of one head are 8 consecutive,
// 8-aligned lanes).
// ---------------------------------------------------------------------------
template<int COLS, int NH>
__global__ __launch_bounds__(256) void gemm_tiled(
    const float* __restrict__ in, const float* __restrict__ W,
    const float* __restrict__ a_s, const float* __restrict__ a_d,
    float* __restrict__ hout, float* __restrict__ asrc, float* __restrict__ adst)
{
    constexpr int CG = COLS / 4;        // col groups   (32 or 8)
    constexpr int NG = 256 / CG;        // node groups  (8 or 32)
    constexpr int TILE_N = NG * 4;      // 32 or 128 nodes per block
    constexpr int KT = 32;              // k tile
    constexpr int XSTR = TILE_N + 4;    // padded stride (36 / 132), 16B-aligned
    constexpr int NTILES = DIM / KT;    // 4

    __shared__ float xs[KT * XSTR];
    __shared__ float Ws[KT * COLS];

    const int tid = threadIdx.x;
    const int c4  = (tid % CG) * 4;     // cols c4..c4+3
    const int n4  = (tid / CG) * 4;     // nodes n0+n4..n0+n4+3
    const int n0  = blockIdx.x * TILE_N;

    float4 acc[4] = {};                 // acc[i] = node n4+i, cols c4..c4+3

    for (int kt = 0; kt < NTILES; ++kt) {
        const int k0 = kt * KT;
        // ---- stage x (transposed) ----
        #pragma unroll
        for (int r = 0; r < TILE_N * KT / 1024; ++r) {
            int fl = tid + 256 * r;
            int nn = fl / (KT / 4);
            int kq = fl % (KT / 4);
            int row = n0 + nn; if (row >= NN) row = NN - 1;
            float4 v = *(const float4*)&in[(long long)row * DIM + k0 + kq * 4];
            xs[(kq * 4 + 0) * XSTR + nn] = v.x;
            xs[(kq * 4 + 1) * XSTR + nn] = v.y;
            xs[(kq * 4 + 2) * XSTR + nn] = v.z;
            xs[(kq * 4 + 3) * XSTR + nn] = v.w;
        }
        // ---- stage W ----
        #pragma unroll
        for (int r = 0; r < KT * COLS / 1024; ++r) {
            int fl = tid + 256 * r;
            int kk = fl / (COLS / 4);
            int cq = fl % (COLS / 4);
            *(float4*)&Ws[kk * COLS + cq * 4] =
                *(const float4*)&W[(long long)(k0 + kk) * COLS + cq * 4];
        }
        __syncthreads();
        // ---- compute ----
        #pragma unroll 8
        for (int k = 0; k < KT; ++k) {
            float4 wv = *(const float4*)&Ws[k * COLS + c4];
            float4 xv = *(const float4*)&xs[k * XSTR + n4];
            acc[0].x = fmaf(xv.x, wv.x, acc[0].x);
            acc[0].y = fmaf(xv.x, wv.y, acc[0].y);
            acc[0].z = fmaf(xv.x, wv.z, acc[0].z);
            acc[0].w = fmaf(xv.x, wv.w, acc[0].w);
            acc[1].x = fmaf(xv.y, wv.x, acc[1].x);
            acc[1].y = fmaf(xv.y, wv.y, acc[1].y);
            acc[1].z = fmaf(xv.y, wv.z, acc[1].z);
            acc[1].w = fmaf(xv.y, wv.w, acc[1].w);
            acc[2].x = fmaf(xv.z, wv.x, acc[2].x);
            acc[2].y = fmaf(xv.z, wv.y, acc[2].y);
            acc[2].z = fmaf(xv.z, wv.z, acc[2].z);
            acc[2].w = fmaf(xv.z, wv.w, acc[2].w);
            acc[3].x = fmaf(xv.w, wv.x, acc[3].x);
            acc[3].y = fmaf(xv.w, wv.y, acc[3].y);
            acc[3].z = fmaf(xv.w, wv.z, acc[3].z);
            acc[3].w = fmaf(xv.w, wv.w, acc[3].w);
        }
        __syncthreads();
    }

    // ---- epilogue: store h + fused alpha reduction ----
    const float4 as4 = *(const float4*)&a_s[c4];
    const float4 ad4 = *(const float4*)&a_d[c4];
    const int head = c4 / 32;           // 0..NH-1 (0 for COLS=32)

    #pragma unroll
    for (int i = 0; i < 4; ++i) {
        const int node = n0 + n4 + i;
        const bool ok = node < NN;
        if (ok)
            *(float4*)&hout[(long long)node * COLS + c4] = acc[i];
        float ps = acc[i].x * as4.x + acc[i].y * as4.y
                 + acc[i].z * as4.z + acc[i].w * as4.w;
        float pd = acc[i].x * ad4.x + acc[i].y * ad4.y
                 + acc[i].z * ad4.z + acc[i].w * ad4.w;
        ps += __shfl_down(ps, 4, 8);
        ps += __shfl_down(ps, 2, 8);
        ps += __shfl_down(ps, 1, 8);
        pd += __shfl_down(pd, 4, 8);
        pd += __shfl_down(pd, 2, 8);
        pd += __shfl_down(pd, 1, 8);
        if (ok && (tid & 7) == 0) {
            asrc[node * NH + head] = ps;
            adst[node * NH + head] = pd;
        }
    }
}

// ---------------------------------------------------------------------------
// CSR construction by dst:  histogram -> exclusive scan -> scatter.
// ---------------------------------------------------------------------------
__global__ void hist_kernel(const int* __restrict__ ei, int* __restrict__ counts)
{
    int e = blockIdx.x * 256 + threadIdx.x;
    if (e >= E2C) return;
    int d = (e < EE) ? ei[EE + e] : e - EE;
    atomicAdd(&counts[d], 1);
}

__global__ void scan1(const int* __restrict__ counts, int* __restrict__ rowptr,
                      int* __restrict__ partials)
{
    __shared__ int tmp[256];
    int i = blockIdx.x * 256 + threadIdx.x;
    int v = (i < NN) ? counts[i] : 0;
    tmp[threadIdx.x] = v;
    __syncthreads();
    for (int off = 1; off < 256; off <<= 1) {
        int t = (threadIdx.x >= off) ? tmp[threadIdx.x - off] : 0;
        __syncthreads();
        tmp[threadIdx.x] += t;
        __syncthreads();
    }
    if (i < NN) rowptr[i] = tmp[threadIdx.x] - v;
    if (threadIdx.x == 255) partials[blockIdx.x] = tmp[255];
}

__global__ void scan2(int* __restrict__ partials)    // single block of 256
{
    __shared__ int tmp[256];
    int v = (threadIdx.x < SCAN_B) ? partials[threadIdx.x] : 0;
    tmp[threadIdx.x] = v;
    __syncthreads();
    for (int off = 1; off < 256; off <<= 1) {
        int t = (threadIdx.x >= off) ? tmp[threadIdx.x - off] : 0;
        __syncthreads();
        tmp[threadIdx.x] += t;
        __syncthreads();
    }
    if (threadIdx.x < SCAN_B) partials[threadIdx.x] = tmp[threadIdx.x] - v;
}

__global__ void scan3(int* __restrict__ rowptr, int* __restrict__ cursor,
                      const int* __restrict__ partials)
{
    int i = blockIdx.x * 256 + threadIdx.x;
    if (i < NN) {
        int v = rowptr[i] + partials[blockIdx.x];
        rowptr[i] = v;
        cursor[i] = v;
    }
    if (i == 0) rowptr[NN] = E2C;
}

__global__ void scatter_kernel(const int* __restrict__ ei, int* __restrict__ cursor,
                               int* __restrict__ sorted_src)
{
    int e = blockIdx.x * 256 + threadIdx.x;
    if (e >= E2C) return;
    int s, d;
    if (e < EE) { s = ei[e]; d = ei[EE + e]; } else { s = d = e - EE; }
    int pos = atomicAdd(&cursor[d], 1);
    sorted_src[pos] = s;
}

// ---------------------------------------------------------------------------
// CSR gather aggregation, float4 per thread + 4-edge batching.
// ---------------------------------------------------------------------------
template<int COLS, int NH, bool DO_ELU>
__global__ __launch_bounds__(256) void aggr_csr4(
    const int* __restrict__ rowptr, const int* __restrict__ sorted_src,
    const float* __restrict__ hin,
    const float* __restrict__ asrc, const float* __restrict__ adst,
    const float* __restrict__ bias, float* __restrict__ out)
{
    constexpr int TPN = COLS / 4;             // threads per node: 32 or 8
    int t = blockIdx.x * 256 + threadIdx.x;
    int d = t / TPN;
    int lc = t % TPN;                         // owns channels 4*lc .. 4*lc+3
    if (d >= NN) return;
    const int head = (4 * lc) >> 5;           // 0..NH-1
    const float ad = adst[d * NH + head];
    const int beg = rowptr[d], end = rowptr[d + 1];

    float4 num = {0.f, 0.f, 0.f, 0.f};
    float den = 0.f;
    int i = beg;
    for (; i + 4 <= end; i += 4) {
        int s0 = sorted_src[i];
        int s1 = sorted_src[i + 1];
        int s2 = sorted_src[i + 2];
        int s3 = sorted_src[i + 3];
        float a0 = asrc[s0 * NH + head];
        float a1 = asrc[s1 * NH + head];
        float a2 = asrc[s2 * NH + head];
        float a3 = asrc[s3 * NH + head];
        float4 h0 = *(const float4*)&hin[(long long)s0 * COLS + 4 * lc];
        float4 h1 = *(const float4*)&hin[(long long)s1 * COLS + 4 * lc];
        float4 h2 = *(const float4*)&hin[(long long)s2 * COLS + 4 * lc];
        float4 h3 = *(const float4*)&hin[(long long)s3 * COLS + 4 * lc];
        float l0 = a0 + ad; l0 = l0 > 0.f ? l0 : 0.2f * l0;
        float l1 = a1 + ad; l1 = l1 > 0.f ? l1 : 0.2f * l1;
        float l2 = a2 + ad; l2 = l2 > 0.f ? l2 : 0.2f * l2;
        float l3 = a3 + ad; l3 = l3 > 0.f ? l3 : 0.2f * l3;
        float w0 = __builtin_expf(l0);
        float w1 = __builtin_expf(l1);
        float w2 = __builtin_expf(l2);
        float w3 = __builtin_expf(l3);
        den += (w0 + w1) + (w2 + w3);
        num.x = fmaf(w0, h0.x, num.x); num.y = fmaf(w0, h0.y, num.y);
        num.z = fmaf(w0, h0.z, num.z); num.w = fmaf(w0, h0.w, num.w);
        num.x = fmaf(w1, h1.x, num.x); num.y = fmaf(w1, h1.y, num.y);
        num.z = fmaf(w1, h1.z, num.z); num.w = fmaf(w1, h1.w, num.w);
        num.x = fmaf(w2, h2.x, num.x); num.y = fmaf(w2, h2.y, num.y);
        num.z = fmaf(w2, h2.z, num.z); num.w = fmaf(w2, h2.w, num.w);
        num.x = fmaf(w3, h3.x, num.x); num.y = fmaf(w3, h3.y, num.y);
        num.z = fmaf(w3, h3.z, num.z); num.w = fmaf(w3, h3.w, num.w);
    }
    for (; i < end; ++i) {
        int s = sorted_src[i];
        float a = asrc[s * NH + head];
        float4 h = *(const float4*)&hin[(long long)s * COLS + 4 * lc];
        float l = a + ad; l = l > 0.f ? l : 0.2f * l;
        float w = __builtin_expf(l);
        den += w;
        num.x = fmaf(w, h.x, num.x); num.y = fmaf(w, h.y, num.y);
        num.z = fmaf(w, h.z, num.z); num.w = fmaf(w, h.w, num.w);
    }

    float inv = 1.f / (den + 1e-16f);
    const float4 b4 = *(const float4*)&bias[4 * lc];
    float4 v;
    v.x = num.x * inv + b4.x;
    v.y = num.y * inv + b4.y;
    v.z = num.z * inv + b4.z;
    v.w = num.w * inv + b4.w;
    if (DO_ELU) {
        v.x = v.x > 0.f ? v.x : expm1f(v.x);
        v.y = v.y > 0.f ? v.y : expm1f(v.y);
        v.z = v.z > 0.f ? v.z : expm1f(v.z);
        v.w = v.w > 0.f ? v.w : expm1f(v.w);
    }
    *(float4*)&out[(long long)d * COLS + 4 * lc] = v;
}

// ---------------------------------------------------------------------------
extern "C" void kernel_launch(void* const* d_in, const int* in_sizes, int n_in,
                              void* d_out, int out_size, void* d_ws, size_t ws_size,
                              hipStream_t stream)
{
    const float* x   = (const float*)d_in[0];
    const int*   ei  = (const int*)  d_in[1];
    const float* W1  = (const float*)d_in[2];
    const float* as1 = (const float*)d_in[3];
    const float* ad1 = (const float*)d_in[4];
    const float* b1  = (const float*)d_in[5];
    const float* W2  = (const float*)d_in[6];
    const float* as2 = (const float*)d_in[7];
    const float* ad2 = (const float*)d_in[8];
    const float* b2  = (const float*)d_in[9];
    const float* W3  = (const float*)d_in[10];
    const float* as3 = (const float*)d_in[11];
    const float* ad3 = (const float*)d_in[12];
    const float* b3  = (const float*)d_in[13];
    float* out = (float*)d_out;

    // workspace layout
    float* ws   = (float*)d_ws;
    float* H    = ws;                          // N*128 f
    float* O    = H    + (size_t)NN * 128;     // N*128 f
    float* ASRC = O    + (size_t)NN * 128;     // N*4 f
    float* ADST = ASRC + (size_t)NN * 4;       // N*4 f
    int* rowptr = (int*)(ADST + (size_t)NN * 4);          // NN+1
    int* cursor = rowptr + (NN + 1);                      // NN (also histogram)
    int* sorted = cursor + NN;                            // E2C
    int* partials = sorted + E2C;                         // SCAN_B

    const int gEdge = (E2C + 255) / 256;                 // 3321
    const int gAggr128 = (NN * 32 + 255) / 256;          // 6250
    const int gAggr32  = (NN * 8 + 255) / 256;           // 1563
    const int gGemm128 = (NN + 31) / 32;                 // 1563
    const int gGemm32  = (NN + 127) / 128;               // 391

    // ---- build CSR (dst-sorted) once; reused by all 3 layers ----
    hipMemsetAsync(cursor, 0, (size_t)NN * sizeof(int), stream);
    hist_kernel<<<gEdge, 256, 0, stream>>>(ei, cursor);
    scan1<<<SCAN_B, 256, 0, stream>>>(cursor, rowptr, partials);
    scan2<<<1, 256, 0, stream>>>(partials);
    scan3<<<SCAN_B, 256, 0, stream>>>(rowptr, cursor, partials);
    scatter_kernel<<<gEdge, 256, 0, stream>>>(ei, cursor, sorted);

    // ---- layer 1 (128 -> 4x32 concat, ELU) ----
    gemm_tiled<128, 4><<<gGemm128, 256, 0, stream>>>(x, W1, as1, ad1, H, ASRC, ADST);
    aggr_csr4<128, 4, true><<<gAggr128, 256, 0, stream>>>(rowptr, sorted, H, ASRC, ADST, b1, O);

    // ---- layer 2 (128 -> 4x32 concat, ELU) ----
    gemm_tiled<128, 4><<<gGemm128, 256, 0, stream>>>(O, W2, as2, ad2, H, ASRC, ADST);
    aggr_csr4<128, 4, true><<<gAggr128, 256, 0, stream>>>(rowptr, sorted, H, ASRC, ADST, b2, O);

    // ---- layer 3 (128 -> 32, 1 head, no concat) ----
    gemm_tiled<32, 1><<<gGemm32, 256, 0, stream>>>(O, W3, as3, ad3, H, ASRC, ADST);
    aggr_csr4<32, 1, false><<<gAggr32, 256, 0, stream>>>(rowptr, sorted, H, ASRC, ADST, b3, out);
}

// Round 5
// 376.647 us; speedup vs baseline: 4.2289x; 1.0984x over previous
//
#include <hip/hip_runtime.h>
#include <cmath>

constexpr int NN  = 50000;          // nodes
constexpr int EE  = 800000;         // raw edges
constexpr int E2C = EE + NN;        // edges incl. self loops = 850000
constexpr int DIM = 128;            // input dim to every layer's GEMM
constexpr int SCAN_B = (NN + 255) / 256;   // 196 scan blocks

// bf16 helpers: h is stored bf16 (gather payload); all math in fp32.
__device__ inline unsigned bf16rne(float f) {
    unsigned u = __builtin_bit_cast(unsigned, f);
    return (u + 0x7fffu + ((u >> 16) & 1u)) >> 16;     // round-nearest-even
}
__device__ inline float bflo(unsigned u) { return __builtin_bit_cast(float, u << 16); }
__device__ inline float bfhi(unsigned u) { return __builtin_bit_cast(float, u & 0xffff0000u); }

// ---------------------------------------------------------------------------
// LDS-tiled GEMM  in[N,128] @ W[128,COLS]  + fused attention coefficients.
// 256 threads; 4 x CPT register tile per thread. h output stored as bf16.
// COLS=128,CPT=8: 64 nodes/block.  COLS=32,CPT=4: 128 nodes/block.
// ---------------------------------------------------------------------------
template<int COLS, int NH, int CPT>
__global__ __launch_bounds__(256) void gemm_tiled(
    const float* __restrict__ in, const float* __restrict__ W,
    const float* __restrict__ a_s, const float* __restrict__ a_d,
    unsigned short* __restrict__ hout, float* __restrict__ asrc, float* __restrict__ adst)
{
    constexpr int CG = COLS / CPT;      // col groups (16 or 8)
    constexpr int NG = 256 / CG;        // node groups (16 or 32)
    constexpr int TILE_N = NG * 4;      // 64 or 128 nodes per block
    constexpr int KT = 32;              // k tile
    constexpr int XSTR = TILE_N + 4;    // padded stride, 16B-aligned
    constexpr int NTILES = DIM / KT;    // 4
    constexpr int RL = 32 / CPT;        // lanes per head-row (4 or 8)

    __shared__ float xs[KT * XSTR];
    __shared__ float Ws[KT * COLS];

    const int tid = threadIdx.x;
    const int cc  = (tid % CG) * CPT;   // cols cc..cc+CPT-1
    const int n4  = (tid / CG) * 4;     // nodes n0+n4..n0+n4+3
    const int n0  = blockIdx.x * TILE_N;

    float acc[4][CPT] = {};

    for (int kt = 0; kt < NTILES; ++kt) {
        const int k0 = kt * KT;
        // ---- stage x (transposed) ----
        #pragma unroll
        for (int r = 0; r < TILE_N * KT / 1024; ++r) {
            int fl = tid + 256 * r;
            int nn = fl / (KT / 4);
            int kq = fl % (KT / 4);
            int row = n0 + nn; if (row >= NN) row = NN - 1;
            float4 v = *(const float4*)&in[(long long)row * DIM + k0 + kq * 4];
            xs[(kq * 4 + 0) * XSTR + nn] = v.x;
            xs[(kq * 4 + 1) * XSTR + nn] = v.y;
            xs[(kq * 4 + 2) * XSTR + nn] = v.z;
            xs[(kq * 4 + 3) * XSTR + nn] = v.w;
        }
        // ---- stage W ----
        #pragma unroll
        for (int r = 0; r < KT * COLS / 1024; ++r) {
            int fl = tid + 256 * r;
            int kk = fl / (COLS / 4);
            int cq = fl % (COLS / 4);
            *(float4*)&Ws[kk * COLS + cq * 4] =
                *(const float4*)&W[(long long)(k0 + kk) * COLS + cq * 4];
        }
        __syncthreads();
        // ---- compute ----
        #pragma unroll 8
        for (int k = 0; k < KT; ++k) {
            float4 xv4 = *(const float4*)&xs[k * XSTR + n4];
            float xv[4] = {xv4.x, xv4.y, xv4.z, xv4.w};
            float wv[CPT];
            #pragma unroll
            for (int q = 0; q < CPT / 4; ++q) {
                float4 w4 = *(const float4*)&Ws[k * COLS + cc + 4 * q];
                wv[4 * q + 0] = w4.x; wv[4 * q + 1] = w4.y;
                wv[4 * q + 2] = w4.z; wv[4 * q + 3] = w4.w;
            }
            #pragma unroll
            for (int i = 0; i < 4; ++i)
                #pragma unroll
                for (int j = 0; j < CPT; ++j)
                    acc[i][j] = fmaf(xv[i], wv[j], acc[i][j]);
        }
        __syncthreads();
    }

    // ---- epilogue: bf16 store + fused alpha reduction ----
    float asv[CPT], adv[CPT];
    #pragma unroll
    for (int j = 0; j < CPT; ++j) { asv[j] = a_s[cc + j]; adv[j] = a_d[cc + j]; }
    const int head = cc / 32;

    #pragma unroll
    for (int i = 0; i < 4; ++i) {
        const int node = n0 + n4 + i;
        const bool ok = node < NN;
        unsigned up[CPT / 2];
        #pragma unroll
        for (int j = 0; j < CPT / 2; ++j)
            up[j] = bf16rne(acc[i][2 * j]) | (bf16rne(acc[i][2 * j + 1]) << 16);
        if (ok) {
            if constexpr (CPT == 8) {
                uint4 t4; t4.x = up[0]; t4.y = up[1]; t4.z = up[2]; t4.w = up[3];
                *(uint4*)&hout[(long long)node * COLS + cc] = t4;
            } else {
                uint2 t2; t2.x = up[0]; t2.y = up[1];
                *(uint2*)&hout[(long long)node * COLS + cc] = t2;
            }
        }
        float ps = 0.f, pd = 0.f;
        #pragma unroll
        for (int j = 0; j < CPT; ++j) {
            ps = fmaf(acc[i][j], asv[j], ps);
            pd = fmaf(acc[i][j], adv[j], pd);
        }
        #pragma unroll
        for (int off = RL / 2; off > 0; off >>= 1) {
            ps += __shfl_down(ps, off, RL);
            pd += __shfl_down(pd, off, RL);
        }
        if (ok && (tid & (RL - 1)) == 0) {
            asrc[node * NH + head] = ps;
            adst[node * NH + head] = pd;
        }
    }
}

// ---------------------------------------------------------------------------
// CSR construction by dst:  histogram -> exclusive scan -> scatter.
// ---------------------------------------------------------------------------
__global__ void hist_kernel(const int* __restrict__ ei, int* __restrict__ counts)
{
    int e = blockIdx.x * 256 + threadIdx.x;
    if (e >= E2C) return;
    int d = (e < EE) ? ei[EE + e] : e - EE;
    atomicAdd(&counts[d], 1);
}

__global__ void scan1(const int* __restrict__ counts, int* __restrict__ rowptr,
                      int* __restrict__ partials)
{
    __shared__ int tmp[256];
    int i = blockIdx.x * 256 + threadIdx.x;
    int v = (i < NN) ? counts[i] : 0;
    tmp[threadIdx.x] = v;
    __syncthreads();
    for (int off = 1; off < 256; off <<= 1) {
        int t = (threadIdx.x >= off) ? tmp[threadIdx.x - off] : 0;
        __syncthreads();
        tmp[threadIdx.x] += t;
        __syncthreads();
    }
    if (i < NN) rowptr[i] = tmp[threadIdx.x] - v;
    if (threadIdx.x == 255) partials[blockIdx.x] = tmp[255];
}

__global__ void scan2(int* __restrict__ partials)    // single block of 256
{
    __shared__ int tmp[256];
    int v = (threadIdx.x < SCAN_B) ? partials[threadIdx.x] : 0;
    tmp[threadIdx.x] = v;
    __syncthreads();
    for (int off = 1; off < 256; off <<= 1) {
        int t = (threadIdx.x >= off) ? tmp[threadIdx.x - off] : 0;
        __syncthreads();
        tmp[threadIdx.x] += t;
        __syncthreads();
    }
    if (threadIdx.x < SCAN_B) partials[threadIdx.x] = tmp[threadIdx.x] - v;
}

__global__ void scan3(int* __restrict__ rowptr, int* __restrict__ cursor,
                      const int* __restrict__ partials)
{
    int i = blockIdx.x * 256 + threadIdx.x;
    if (i < NN) {
        int v = rowptr[i] + partials[blockIdx.x];
        rowptr[i] = v;
        cursor[i] = v;
    }
    if (i == 0) rowptr[NN] = E2C;
}

__global__ void scatter_kernel(const int* __restrict__ ei, int* __restrict__ cursor,
                               int* __restrict__ sorted_src)
{
    int e = blockIdx.x * 256 + threadIdx.x;
    if (e >= E2C) return;
    int s, d;
    if (e < EE) { s = ei[e]; d = ei[EE + e]; } else { s = d = e - EE; }
    int pos = atomicAdd(&cursor[d], 1);
    sorted_src[pos] = s;
}

// ---------------------------------------------------------------------------
// CSR gather aggregation over bf16 h: 8 channels/lane (one uint4 = 16B load),
// 4-edge batching. COLS/8 lanes per dst node. fp32 accumulate + fp32 output.
// ---------------------------------------------------------------------------
template<int COLS, int NH, bool DO_ELU>
__global__ __launch_bounds__(256) void aggr_csr(
    const int* __restrict__ rowptr, const int* __restrict__ sorted_src,
    const unsigned short* __restrict__ hin,
    const float* __restrict__ asrc, const float* __restrict__ adst,
    const float* __restrict__ bias, float* __restrict__ out)
{
    constexpr int TPN = COLS / 8;             // lanes per node: 16 or 4
    constexpr int USTR = COLS / 2;            // uints per h row
    int t = blockIdx.x * 256 + threadIdx.x;
    int d = t / TPN;
    int lc = t % TPN;                         // owns channels 8*lc .. 8*lc+7
    if (d >= NN) return;
    const int cc = lc * 8;
    const int head = cc / 32;                 // 0..NH-1
    const float ad = adst[d * NH + head];
    const int beg = rowptr[d], end = rowptr[d + 1];
    const uint* hp = (const uint*)hin;

    float num[8] = {};
    float den = 0.f;

    auto accum = [&](float w, uint4 H) {
        den += w;
        num[0] = fmaf(w, bflo(H.x), num[0]); num[1] = fmaf(w, bfhi(H.x), num[1]);
        num[2] = fmaf(w, bflo(H.y), num[2]); num[3] = fmaf(w, bfhi(H.y), num[3]);
        num[4] = fmaf(w, bflo(H.z), num[4]); num[5] = fmaf(w, bfhi(H.z), num[5]);
        num[6] = fmaf(w, bflo(H.w), num[6]); num[7] = fmaf(w, bfhi(H.w), num[7]);
    };

    int i = beg;
    for (; i + 4 <= end; i += 4) {
        int s0 = sorted_src[i];
        int s1 = sorted_src[i + 1];
        int s2 = sorted_src[i + 2];
        int s3 = sorted_src[i + 3];
        float a0 = asrc[s0 * NH + head];
        float a1 = asrc[s1 * NH + head];
        float a2 = asrc[s2 * NH + head];
        float a3 = asrc[s3 * NH + head];
        uint4 H0 = *(const uint4*)&hp[(long long)s0 * USTR + cc / 2];
        uint4 H1 = *(const uint4*)&hp[(long long)s1 * USTR + cc / 2];
        uint4 H2 = *(const uint4*)&hp[(long long)s2 * USTR + cc / 2];
        uint4 H3 = *(const uint4*)&hp[(long long)s3 * USTR + cc / 2];
        float l0 = a0 + ad; l0 = l0 > 0.f ? l0 : 0.2f * l0;
        float l1 = a1 + ad; l1 = l1 > 0.f ? l1 : 0.2f * l1;
        float l2 = a2 + ad; l2 = l2 > 0.f ? l2 : 0.2f * l2;
        float l3 = a3 + ad; l3 = l3 > 0.f ? l3 : 0.2f * l3;
        accum(__builtin_expf(l0), H0);
        accum(__builtin_expf(l1), H1);
        accum(__builtin_expf(l2), H2);
        accum(__builtin_expf(l3), H3);
    }
    for (; i < end; ++i) {
        int s = sorted_src[i];
        float a = asrc[s * NH + head];
        uint4 H = *(const uint4*)&hp[(long long)s * USTR + cc / 2];
        float l = a + ad; l = l > 0.f ? l : 0.2f * l;
        accum(__builtin_expf(l), H);
    }

    float inv = 1.f / (den + 1e-16f);
    float v[8];
    #pragma unroll
    for (int j = 0; j < 8; ++j) {
        v[j] = num[j] * inv + bias[cc + j];
        if (DO_ELU) v[j] = v[j] > 0.f ? v[j] : expm1f(v[j]);
    }
    float4 o0 = {v[0], v[1], v[2], v[3]};
    float4 o1 = {v[4], v[5], v[6], v[7]};
    *(float4*)&out[(long long)d * COLS + cc]     = o0;
    *(float4*)&out[(long long)d * COLS + cc + 4] = o1;
}

// ---------------------------------------------------------------------------
extern "C" void kernel_launch(void* const* d_in, const int* in_sizes, int n_in,
                              void* d_out, int out_size, void* d_ws, size_t ws_size,
                              hipStream_t stream)
{
    const float* x   = (const float*)d_in[0];
    const int*   ei  = (const int*)  d_in[1];
    const float* W1  = (const float*)d_in[2];
    const float* as1 = (const float*)d_in[3];
    const float* ad1 = (const float*)d_in[4];
    const float* b1  = (const float*)d_in[5];
    const float* W2  = (const float*)d_in[6];
    const float* as2 = (const float*)d_in[7];
    const float* ad2 = (const float*)d_in[8];
    const float* b2  = (const float*)d_in[9];
    const float* W3  = (const float*)d_in[10];
    const float* as3 = (const float*)d_in[11];
    const float* ad3 = (const float*)d_in[12];
    const float* b3  = (const float*)d_in[13];
    float* out = (float*)d_out;

    // workspace layout
    unsigned short* H = (unsigned short*)d_ws;            // N*128 bf16 (12.8 MB)
    float* O    = (float*)(H + (size_t)NN * 128);         // N*128 f
    float* ASRC = O + (size_t)NN * 128;                   // N*4 f
    float* ADST = ASRC + (size_t)NN * 4;                  // N*4 f
    int* rowptr = (int*)(ADST + (size_t)NN * 4);          // NN+1
    int* cursor = rowptr + (NN + 1);                      // NN (also histogram)
    int* sorted = cursor + NN;                            // E2C
    int* partials = sorted + E2C;                         // SCAN_B

    const int gEdge = (E2C + 255) / 256;                 // 3321
    const int gGemm128 = (NN + 63) / 64;                 // 782
    const int gGemm32  = (NN + 127) / 128;               // 391
    const int gAggr128 = (NN * 16 + 255) / 256;          // 3125
    const int gAggr32  = (NN * 4 + 255) / 256;           // 782

    // ---- build CSR (dst-sorted) once; reused by all 3 layers ----
    hipMemsetAsync(cursor, 0, (size_t)NN * sizeof(int), stream);
    hist_kernel<<<gEdge, 256, 0, stream>>>(ei, cursor);
    scan1<<<SCAN_B, 256, 0, stream>>>(cursor, rowptr, partials);
    scan2<<<1, 256, 0, stream>>>(partials);
    scan3<<<SCAN_B, 256, 0, stream>>>(rowptr, cursor, partials);
    scatter_kernel<<<gEdge, 256, 0, stream>>>(ei, cursor, sorted);

    // ---- layer 1 (128 -> 4x32 concat, ELU) ----
    gemm_tiled<128, 4, 8><<<gGemm128, 256, 0, stream>>>(x, W1, as1, ad1, H, ASRC, ADST);
    aggr_csr<128, 4, true><<<gAggr128, 256, 0, stream>>>(rowptr, sorted, H, ASRC, ADST, b1, O);

    // ---- layer 2 (128 -> 4x32 concat, ELU) ----
    gemm_tiled<128, 4, 8><<<gGemm128, 256, 0, stream>>>(O, W2, as2, ad2, H, ASRC, ADST);
    aggr_csr<128, 4, true><<<gAggr128, 256, 0, stream>>>(rowptr, sorted, H, ASRC, ADST, b2, O);

    // ---- layer 3 (128 -> 32, 1 head, no concat) ----
    gemm_tiled<32, 1, 4><<<gGemm32, 256, 0, stream>>>(O, W3, as3, ad3, H, ASRC, ADST);
    aggr_csr<32, 1, false><<<gAggr32, 256, 0, stream>>>(rowptr, sorted, H, ASRC, ADST, b3, out);
}

// Round 6
// 349.646 us; speedup vs baseline: 4.5555x; 1.0772x over previous
//
#include <hip/hip_runtime.h>
#include <cmath>

constexpr int NN  = 50000;          // nodes
constexpr int EE  = 800000;         // raw edges
constexpr int E2C = EE + NN;        // edges incl. self loops = 850000
constexpr int DIM = 128;            // input dim to every layer's GEMM
constexpr int SCAN_B = (NN + 255) / 256;   // 196 scan blocks

// bucketed counting sort params
constexpr int NBUCK = 256;          // dst buckets
constexpr int BW    = 196;          // bucket width: 196*256 = 50176 >= NN
constexpr int EPT   = 16;           // edges per thread (phase B)
constexpr int CH    = 256 * EPT;    // 4096 edges per phase-B block
constexpr int NB_B  = (E2C + CH - 1) / CH;  // 208 blocks

// bf16 helpers: h is stored bf16 (gather payload); all math in fp32.
__device__ inline unsigned bf16rne(float f) {
    unsigned u = __builtin_bit_cast(unsigned, f);
    return (u + 0x7fffu + ((u >> 16) & 1u)) >> 16;     // round-nearest-even
}
__device__ inline float bflo(unsigned u) { return __builtin_bit_cast(float, u << 16); }
__device__ inline float bfhi(unsigned u) { return __builtin_bit_cast(float, u & 0xffff0000u); }

// ---------------------------------------------------------------------------
// LDS-tiled GEMM  in[N,128] @ W[128,COLS]  + fused attention coefficients.
// 256 threads; 4 x CPT register tile per thread. h output stored as bf16.
// ---------------------------------------------------------------------------
template<int COLS, int NH, int CPT>
__global__ __launch_bounds__(256) void gemm_tiled(
    const float* __restrict__ in, const float* __restrict__ W,
    const float* __restrict__ a_s, const float* __restrict__ a_d,
    unsigned short* __restrict__ hout, float* __restrict__ asrc, float* __restrict__ adst)
{
    constexpr int CG = COLS / CPT;      // col groups (16 or 8)
    constexpr int NG = 256 / CG;        // node groups (16 or 32)
    constexpr int TILE_N = NG * 4;      // 64 or 128 nodes per block
    constexpr int KT = 32;              // k tile
    constexpr int XSTR = TILE_N + 4;    // padded stride, 16B-aligned
    constexpr int NTILES = DIM / KT;    // 4
    constexpr int RL = 32 / CPT;        // lanes per head-row (4 or 8)

    __shared__ float xs[KT * XSTR];
    __shared__ float Ws[KT * COLS];

    const int tid = threadIdx.x;
    const int cc  = (tid % CG) * CPT;   // cols cc..cc+CPT-1
    const int n4  = (tid / CG) * 4;     // nodes n0+n4..n0+n4+3
    const int n0  = blockIdx.x * TILE_N;

    float acc[4][CPT] = {};

    for (int kt = 0; kt < NTILES; ++kt) {
        const int k0 = kt * KT;
        // ---- stage x (transposed) ----
        #pragma unroll
        for (int r = 0; r < TILE_N * KT / 1024; ++r) {
            int fl = tid + 256 * r;
            int nn = fl / (KT / 4);
            int kq = fl % (KT / 4);
            int row = n0 + nn; if (row >= NN) row = NN - 1;
            float4 v = *(const float4*)&in[(long long)row * DIM + k0 + kq * 4];
            xs[(kq * 4 + 0) * XSTR + nn] = v.x;
            xs[(kq * 4 + 1) * XSTR + nn] = v.y;
            xs[(kq * 4 + 2) * XSTR + nn] = v.z;
            xs[(kq * 4 + 3) * XSTR + nn] = v.w;
        }
        // ---- stage W ----
        #pragma unroll
        for (int r = 0; r < KT * COLS / 1024; ++r) {
            int fl = tid + 256 * r;
            int kk = fl / (COLS / 4);
            int cq = fl % (COLS / 4);
            *(float4*)&Ws[kk * COLS + cq * 4] =
                *(const float4*)&W[(long long)(k0 + kk) * COLS + cq * 4];
        }
        __syncthreads();
        // ---- compute ----
        #pragma unroll 8
        for (int k = 0; k < KT; ++k) {
            float4 xv4 = *(const float4*)&xs[k * XSTR + n4];
            float xv[4] = {xv4.x, xv4.y, xv4.z, xv4.w};
            float wv[CPT];
            #pragma unroll
            for (int q = 0; q < CPT / 4; ++q) {
                float4 w4 = *(const float4*)&Ws[k * COLS + cc + 4 * q];
                wv[4 * q + 0] = w4.x; wv[4 * q + 1] = w4.y;
                wv[4 * q + 2] = w4.z; wv[4 * q + 3] = w4.w;
            }
            #pragma unroll
            for (int i = 0; i < 4; ++i)
                #pragma unroll
                for (int j = 0; j < CPT; ++j)
                    acc[i][j] = fmaf(xv[i], wv[j], acc[i][j]);
        }
        __syncthreads();
    }

    // ---- epilogue: bf16 store + fused alpha reduction ----
    float asv[CPT], adv[CPT];
    #pragma unroll
    for (int j = 0; j < CPT; ++j) { asv[j] = a_s[cc + j]; adv[j] = a_d[cc + j]; }
    const int head = cc / 32;

    #pragma unroll
    for (int i = 0; i < 4; ++i) {
        const int node = n0 + n4 + i;
        const bool ok = node < NN;
        unsigned up[CPT / 2];
        #pragma unroll
        for (int j = 0; j < CPT / 2; ++j)
            up[j] = bf16rne(acc[i][2 * j]) | (bf16rne(acc[i][2 * j + 1]) << 16);
        if (ok) {
            if constexpr (CPT == 8) {
                uint4 t4; t4.x = up[0]; t4.y = up[1]; t4.z = up[2]; t4.w = up[3];
                *(uint4*)&hout[(long long)node * COLS + cc] = t4;
            } else {
                uint2 t2; t2.x = up[0]; t2.y = up[1];
                *(uint2*)&hout[(long long)node * COLS + cc] = t2;
            }
        }
        float ps = 0.f, pd = 0.f;
        #pragma unroll
        for (int j = 0; j < CPT; ++j) {
            ps = fmaf(acc[i][j], asv[j], ps);
            pd = fmaf(acc[i][j], adv[j], pd);
        }
        #pragma unroll
        for (int off = RL / 2; off > 0; off >>= 1) {
            ps += __shfl_down(ps, off, RL);
            pd += __shfl_down(pd, off, RL);
        }
        if (ok && (tid & (RL - 1)) == 0) {
            asrc[node * NH + head] = ps;
            adst[node * NH + head] = pd;
        }
    }
}

// ---------------------------------------------------------------------------
// CSR construction: hist -> scan -> bucket-binning sort (line-local writes).
// ---------------------------------------------------------------------------
__global__ void hist_kernel(const int* __restrict__ ei, int* __restrict__ counts)
{
    int e = blockIdx.x * 256 + threadIdx.x;
    if (e >= E2C) return;
    int d = (e < EE) ? ei[EE + e] : e - EE;
    atomicAdd(&counts[d], 1);
}

__global__ void scan1(const int* __restrict__ counts, int* __restrict__ rowptr,
                      int* __restrict__ partials)
{
    __shared__ int tmp[256];
    int i = blockIdx.x * 256 + threadIdx.x;
    int v = (i < NN) ? counts[i] : 0;
    tmp[threadIdx.x] = v;
    __syncthreads();
    for (int off = 1; off < 256; off <<= 1) {
        int t = (threadIdx.x >= off) ? tmp[threadIdx.x - off] : 0;
        __syncthreads();
        tmp[threadIdx.x] += t;
        __syncthreads();
    }
    if (i < NN) rowptr[i] = tmp[threadIdx.x] - v;
    if (threadIdx.x == 255) partials[blockIdx.x] = tmp[255];
}

__global__ void scan2(int* __restrict__ partials)    // single block of 256
{
    __shared__ int tmp[256];
    int v = (threadIdx.x < SCAN_B) ? partials[threadIdx.x] : 0;
    tmp[threadIdx.x] = v;
    __syncthreads();
    for (int off = 1; off < 256; off <<= 1) {
        int t = (threadIdx.x >= off) ? tmp[threadIdx.x - off] : 0;
        __syncthreads();
        tmp[threadIdx.x] += t;
        __syncthreads();
    }
    if (threadIdx.x < SCAN_B) partials[threadIdx.x] = tmp[threadIdx.x] - v;
}

__global__ void scan3(int* __restrict__ rowptr, const int* __restrict__ partials)
{
    int i = blockIdx.x * 256 + threadIdx.x;
    if (i < NN) rowptr[i] += partials[blockIdx.x];
    if (i == 0) rowptr[NN] = E2C;
}

__global__ void init_bcursor(const int* __restrict__ rowptr, int* __restrict__ bcursor)
{
    int t = threadIdx.x;                       // <<<1, NBUCK>>>
    int n = t * BW; if (n > NN) n = NN;
    bcursor[t] = rowptr[n];
}

// Phase B: bin edges into bucket-grouped pairs array with LDS staging so
// global writes are dense/full-line.
__global__ __launch_bounds__(256) void bucket_bin(
    const int* __restrict__ ei, int* __restrict__ bcursor, uint2* __restrict__ pairs)
{
    __shared__ int cnt[NBUCK];
    __shared__ int scanex[NBUCK];
    __shared__ int base[NBUCK];
    __shared__ int cur[NBUCK];
    __shared__ uint2 stage[CH];

    const int tid = threadIdx.x;
    const long long e0 = (long long)blockIdx.x * CH;
    cnt[tid] = 0;
    __syncthreads();

    int s[EPT], d[EPT], bk[EPT];
    #pragma unroll
    for (int j = 0; j < EPT; ++j) {
        long long e = e0 + tid + j * 256;
        bool valid = e < E2C;
        int ss = 0, dd = 0;
        if (valid) {
            if (e < EE) { ss = ei[e]; dd = ei[EE + e]; }
            else        { ss = dd = (int)(e - EE); }
        }
        s[j] = ss; d[j] = dd;
        bk[j] = valid ? dd / BW : -1;
        if (valid) atomicAdd(&cnt[bk[j]], 1);
    }
    __syncthreads();

    // exclusive scan of cnt (Hillis-Steele over 256) -> scanex
    const int myc = cnt[tid];
    scanex[tid] = myc;
    __syncthreads();
    for (int off = 1; off < NBUCK; off <<= 1) {
        int t = (tid >= off) ? scanex[tid - off] : 0;
        __syncthreads();
        scanex[tid] += t;
        __syncthreads();
    }
    int excl = scanex[tid] - myc;
    __syncthreads();
    scanex[tid] = excl;
    cur[tid]    = excl;
    base[tid]   = atomicAdd(&bcursor[tid], myc);   // reserve global chunk
    __syncthreads();

    // stage pairs in LDS ordered by bucket
    #pragma unroll
    for (int j = 0; j < EPT; ++j) {
        if (bk[j] >= 0) {
            int p = atomicAdd(&cur[bk[j]], 1);
            stage[p] = make_uint2((unsigned)s[j], (unsigned)d[j]);
        }
    }
    __syncthreads();

    // dense flush: consecutive LDS slots -> consecutive global slots per bucket
    const int total = (e0 + CH <= E2C) ? CH : (int)(E2C - e0);
    for (int j = tid; j < total; j += 256) {
        uint2 p = stage[j];
        int b = (int)p.y / BW;
        pairs[base[b] + (j - scanex[b])] = p;
    }
}

// Phase C: one block per bucket; LDS cursors; writes confined to the
// block-exclusive output window -> L2 merges to full-line writebacks.
__global__ __launch_bounds__(256) void bucket_sort(
    const int* __restrict__ rowptr, const uint2* __restrict__ pairs,
    int* __restrict__ sorted_src)
{
    __shared__ int cur[BW];
    const int b  = blockIdx.x;
    const int n0 = b * BW;
    const int n1 = (n0 + BW < NN) ? n0 + BW : NN;
    const int tid = threadIdx.x;
    for (int t = tid; t < n1 - n0; t += 256) cur[t] = rowptr[n0 + t];
    __syncthreads();
    const int beg = rowptr[n0], end = rowptr[n1];
    for (int i = beg + tid; i < end; i += 256) {
        uint2 p = pairs[i];
        int pos = atomicAdd(&cur[(int)p.y - n0], 1);
        sorted_src[pos] = (int)p.x;
    }
}

// ---------------------------------------------------------------------------
// CSR gather aggregation over bf16 h: 8 channels/lane (one uint4 = 16B load),
// 4-edge batching. COLS/8 lanes per dst node. fp32 accumulate + fp32 output.
// ---------------------------------------------------------------------------
template<int COLS, int NH, bool DO_ELU>
__global__ __launch_bounds__(256) void aggr_csr(
    const int* __restrict__ rowptr, const int* __restrict__ sorted_src,
    const unsigned short* __restrict__ hin,
    const float* __restrict__ asrc, const float* __restrict__ adst,
    const float* __restrict__ bias, float* __restrict__ out)
{
    constexpr int TPN = COLS / 8;             // lanes per node: 16 or 4
    constexpr int USTR = COLS / 2;            // uints per h row
    int t = blockIdx.x * 256 + threadIdx.x;
    int d = t / TPN;
    int lc = t % TPN;                         // owns channels 8*lc .. 8*lc+7
    if (d >= NN) return;
    const int cc = lc * 8;
    const int head = cc / 32;                 // 0..NH-1
    const float ad = adst[d * NH + head];
    const int beg = rowptr[d], end = rowptr[d + 1];
    const uint* hp = (const uint*)hin;

    float num[8] = {};
    float den = 0.f;

    auto accum = [&](float w, uint4 H) {
        den += w;
        num[0] = fmaf(w, bflo(H.x), num[0]); num[1] = fmaf(w, bfhi(H.x), num[1]);
        num[2] = fmaf(w, bflo(H.y), num[2]); num[3] = fmaf(w, bfhi(H.y), num[3]);
        num[4] = fmaf(w, bflo(H.z), num[4]); num[5] = fmaf(w, bfhi(H.z), num[5]);
        num[6] = fmaf(w, bflo(H.w), num[6]); num[7] = fmaf(w, bfhi(H.w), num[7]);
    };

    int i = beg;
    for (; i + 4 <= end; i += 4) {
        int s0 = sorted_src[i];
        int s1 = sorted_src[i + 1];
        int s2 = sorted_src[i + 2];
        int s3 = sorted_src[i + 3];
        float a0 = asrc[s0 * NH + head];
        float a1 = asrc[s1 * NH + head];
        float a2 = asrc[s2 * NH + head];
        float a3 = asrc[s3 * NH + head];
        uint4 H0 = *(const uint4*)&hp[(long long)s0 * USTR + cc / 2];
        uint4 H1 = *(const uint4*)&hp[(long long)s1 * USTR + cc / 2];
        uint4 H2 = *(const uint4*)&hp[(long long)s2 * USTR + cc / 2];
        uint4 H3 = *(const uint4*)&hp[(long long)s3 * USTR + cc / 2];
        float l0 = a0 + ad; l0 = l0 > 0.f ? l0 : 0.2f * l0;
        float l1 = a1 + ad; l1 = l1 > 0.f ? l1 : 0.2f * l1;
        float l2 = a2 + ad; l2 = l2 > 0.f ? l2 : 0.2f * l2;
        float l3 = a3 + ad; l3 = l3 > 0.f ? l3 : 0.2f * l3;
        accum(__builtin_expf(l0), H0);
        accum(__builtin_expf(l1), H1);
        accum(__builtin_expf(l2), H2);
        accum(__builtin_expf(l3), H3);
    }
    for (; i < end; ++i) {
        int s = sorted_src[i];
        float a = asrc[s * NH + head];
        uint4 H = *(const uint4*)&hp[(long long)s * USTR + cc / 2];
        float l = a + ad; l = l > 0.f ? l : 0.2f * l;
        accum(__builtin_expf(l), H);
    }

    float inv = 1.f / (den + 1e-16f);
    float v[8];
    #pragma unroll
    for (int j = 0; j < 8; ++j) {
        v[j] = num[j] * inv + bias[cc + j];
        if (DO_ELU) v[j] = v[j] > 0.f ? v[j] : expm1f(v[j]);
    }
    float4 o0 = {v[0], v[1], v[2], v[3]};
    float4 o1 = {v[4], v[5], v[6], v[7]};
    *(float4*)&out[(long long)d * COLS + cc]     = o0;
    *(float4*)&out[(long long)d * COLS + cc + 4] = o1;
}

// ---------------------------------------------------------------------------
extern "C" void kernel_launch(void* const* d_in, const int* in_sizes, int n_in,
                              void* d_out, int out_size, void* d_ws, size_t ws_size,
                              hipStream_t stream)
{
    const float* x   = (const float*)d_in[0];
    const int*   ei  = (const int*)  d_in[1];
    const float* W1  = (const float*)d_in[2];
    const float* as1 = (const float*)d_in[3];
    const float* ad1 = (const float*)d_in[4];
    const float* b1  = (const float*)d_in[5];
    const float* W2  = (const float*)d_in[6];
    const float* as2 = (const float*)d_in[7];
    const float* ad2 = (const float*)d_in[8];
    const float* b2  = (const float*)d_in[9];
    const float* W3  = (const float*)d_in[10];
    const float* as3 = (const float*)d_in[11];
    const float* ad3 = (const float*)d_in[12];
    const float* b3  = (const float*)d_in[13];
    float* out = (float*)d_out;

    // workspace layout
    unsigned short* H = (unsigned short*)d_ws;            // N*128 bf16 (12.8 MB)
    float* O    = (float*)(H + (size_t)NN * 128);         // N*128 f
    float* ASRC = O + (size_t)NN * 128;                   // N*4 f
    float* ADST = ASRC + (size_t)NN * 4;                  // N*4 f
    int* rowptr = (int*)(ADST + (size_t)NN * 4);          // NN+1
    int* counts = rowptr + (NN + 1);                      // NN
    int* sorted = counts + NN;                            // E2C
    int* partials = sorted + E2C;                         // SCAN_B
    int* bcursor  = partials + SCAN_B;                    // NBUCK
    uint2* pairs  = (uint2*)(bcursor + NBUCK + 2);        // E2C uint2 (6.8 MB)

    const int gEdge = (E2C + 255) / 256;                 // 3321
    const int gGemm128 = (NN + 63) / 64;                 // 782
    const int gGemm32  = (NN + 127) / 128;               // 391
    const int gAggr128 = (NN * 16 + 255) / 256;          // 3125
    const int gAggr32  = (NN * 4 + 255) / 256;           // 782

    // ---- build CSR (dst-sorted) once; reused by all 3 layers ----
    hipMemsetAsync(counts, 0, (size_t)NN * sizeof(int), stream);
    hist_kernel<<<gEdge, 256, 0, stream>>>(ei, counts);
    scan1<<<SCAN_B, 256, 0, stream>>>(counts, rowptr, partials);
    scan2<<<1, 256, 0, stream>>>(partials);
    scan3<<<SCAN_B, 256, 0, stream>>>(rowptr, partials);
    init_bcursor<<<1, NBUCK, 0, stream>>>(rowptr, bcursor);
    bucket_bin<<<NB_B, 256, 0, stream>>>(ei, bcursor, pairs);
    bucket_sort<<<NBUCK, 256, 0, stream>>>(rowptr, pairs, sorted);

    // ---- layer 1 (128 -> 4x32 concat, ELU) ----
    gemm_tiled<128, 4, 8><<<gGemm128, 256, 0, stream>>>(x, W1, as1, ad1, H, ASRC, ADST);
    aggr_csr<128, 4, true><<<gAggr128, 256, 0, stream>>>(rowptr, sorted, H, ASRC, ADST, b1, O);

    // ---- layer 2 (128 -> 4x32 concat, ELU) ----
    gemm_tiled<128, 4, 8><<<gGemm128, 256, 0, stream>>>(O, W2, as2, ad2, H, ASRC, ADST);
    aggr_csr<128, 4, true><<<gAggr128, 256, 0, stream>>>(rowptr, sorted, H, ASRC, ADST, b2, O);

    // ---- layer 3 (128 -> 32, 1 head, no concat) ----
    gemm_tiled<32, 1, 4><<<gGemm32, 256, 0, stream>>>(O, W3, as3, ad3, H, ASRC, ADST);
    aggr_csr<32, 1, false><<<gAggr32, 256, 0, stream>>>(rowptr, sorted, H, ASRC, ADST, b3, out);
}

// Round 7
// 334.886 us; speedup vs baseline: 4.7563x; 1.0441x over previous
//
#include <hip/hip_runtime.h>
#include <cmath>

constexpr int NN  = 50000;          // nodes
constexpr int EE  = 800000;         // raw edges
constexpr int E2C = EE + NN;        // edges incl. self loops = 850000
constexpr int DIM = 128;            // input dim to every layer's GEMM

// bucketed counting sort params
constexpr int NBUCK = 256;          // dst buckets
constexpr int BW    = 196;          // bucket width: 196*256 = 50176 >= NN
constexpr int EPT   = 16;           // edges per thread (hist / bin)
constexpr int CH    = 256 * EPT;    // 4096 edges per block
constexpr int NB_B  = (E2C + CH - 1) / CH;  // 208 blocks

// bf16 helpers: h is stored bf16 (gather payload); all math in fp32.
__device__ inline unsigned bf16rne(float f) {
    unsigned u = __builtin_bit_cast(unsigned, f);
    return (u + 0x7fffu + ((u >> 16) & 1u)) >> 16;     // round-nearest-even
}
__device__ inline float bflo(unsigned u) { return __builtin_bit_cast(float, u << 16); }
__device__ inline float bfhi(unsigned u) { return __builtin_bit_cast(float, u & 0xffff0000u); }

// ---------------------------------------------------------------------------
// LDS-tiled GEMM  in[N,128] @ W[128,COLS]  + fused attention coefficients.
// 256 threads; 4 x CPT register tile per thread. h output stored as bf16.
// ---------------------------------------------------------------------------
template<int COLS, int NH, int CPT>
__global__ __launch_bounds__(256) void gemm_tiled(
    const float* __restrict__ in, const float* __restrict__ W,
    const float* __restrict__ a_s, const float* __restrict__ a_d,
    unsigned short* __restrict__ hout, float* __restrict__ asrc, float* __restrict__ adst)
{
    constexpr int CG = COLS / CPT;      // col groups (16 or 8)
    constexpr int NG = 256 / CG;        // node groups (16 or 32)
    constexpr int TILE_N = NG * 4;      // 64 or 128 nodes per block
    constexpr int KT = 32;              // k tile
    constexpr int XSTR = TILE_N + 4;    // padded stride, 16B-aligned
    constexpr int NTILES = DIM / KT;    // 4
    constexpr int RL = 32 / CPT;        // lanes per head-row (4 or 8)

    __shared__ float xs[KT * XSTR];
    __shared__ float Ws[KT * COLS];

    const int tid = threadIdx.x;
    const int cc  = (tid % CG) * CPT;   // cols cc..cc+CPT-1
    const int n4  = (tid / CG) * 4;     // nodes n0+n4..n0+n4+3
    const int n0  = blockIdx.x * TILE_N;

    float acc[4][CPT] = {};

    for (int kt = 0; kt < NTILES; ++kt) {
        const int k0 = kt * KT;
        // ---- stage x (transposed) ----
        #pragma unroll
        for (int r = 0; r < TILE_N * KT / 1024; ++r) {
            int fl = tid + 256 * r;
            int nn = fl / (KT / 4);
            int kq = fl % (KT / 4);
            int row = n0 + nn; if (row >= NN) row = NN - 1;
            float4 v = *(const float4*)&in[(long long)row * DIM + k0 + kq * 4];
            xs[(kq * 4 + 0) * XSTR + nn] = v.x;
            xs[(kq * 4 + 1) * XSTR + nn] = v.y;
            xs[(kq * 4 + 2) * XSTR + nn] = v.z;
            xs[(kq * 4 + 3) * XSTR + nn] = v.w;
        }
        // ---- stage W ----
        #pragma unroll
        for (int r = 0; r < KT * COLS / 1024; ++r) {
            int fl = tid + 256 * r;
            int kk = fl / (COLS / 4);
            int cq = fl % (COLS / 4);
            *(float4*)&Ws[kk * COLS + cq * 4] =
                *(const float4*)&W[(long long)(k0 + kk) * COLS + cq * 4];
        }
        __syncthreads();
        // ---- compute ----
        #pragma unroll 8
        for (int k = 0; k < KT; ++k) {
            float4 xv4 = *(const float4*)&xs[k * XSTR + n4];
            float xv[4] = {xv4.x, xv4.y, xv4.z, xv4.w};
            float wv[CPT];
            #pragma unroll
            for (int q = 0; q < CPT / 4; ++q) {
                float4 w4 = *(const float4*)&Ws[k * COLS + cc + 4 * q];
                wv[4 * q + 0] = w4.x; wv[4 * q + 1] = w4.y;
                wv[4 * q + 2] = w4.z; wv[4 * q + 3] = w4.w;
            }
            #pragma unroll
            for (int i = 0; i < 4; ++i)
                #pragma unroll
                for (int j = 0; j < CPT; ++j)
                    acc[i][j] = fmaf(xv[i], wv[j], acc[i][j]);
        }
        __syncthreads();
    }

    // ---- epilogue: bf16 store + fused alpha reduction ----
    float asv[CPT], adv[CPT];
    #pragma unroll
    for (int j = 0; j < CPT; ++j) { asv[j] = a_s[cc + j]; adv[j] = a_d[cc + j]; }
    const int head = cc / 32;

    #pragma unroll
    for (int i = 0; i < 4; ++i) {
        const int node = n0 + n4 + i;
        const bool ok = node < NN;
        unsigned up[CPT / 2];
        #pragma unroll
        for (int j = 0; j < CPT / 2; ++j)
            up[j] = bf16rne(acc[i][2 * j]) | (bf16rne(acc[i][2 * j + 1]) << 16);
        if (ok) {
            if constexpr (CPT == 8) {
                uint4 t4; t4.x = up[0]; t4.y = up[1]; t4.z = up[2]; t4.w = up[3];
                *(uint4*)&hout[(long long)node * COLS + cc] = t4;
            } else {
                uint2 t2; t2.x = up[0]; t2.y = up[1];
                *(uint2*)&hout[(long long)node * COLS + cc] = t2;
            }
        }
        float ps = 0.f, pd = 0.f;
        #pragma unroll
        for (int j = 0; j < CPT; ++j) {
            ps = fmaf(acc[i][j], asv[j], ps);
            pd = fmaf(acc[i][j], adv[j], pd);
        }
        #pragma unroll
        for (int off = RL / 2; off > 0; off >>= 1) {
            ps += __shfl_down(ps, off, RL);
            pd += __shfl_down(pd, off, RL);
        }
        if (ok && (tid & (RL - 1)) == 0) {
            asrc[node * NH + head] = ps;
            adst[node * NH + head] = pd;
        }
    }
}

// ---------------------------------------------------------------------------
// CSR build: bucket hist (256 buckets) -> 1-block scan -> bucket_bin ->
// bucket_sort (derives per-node rowptr locally in LDS).
// ---------------------------------------------------------------------------
__global__ __launch_bounds__(256) void bucket_hist(
    const int* __restrict__ ei, int* __restrict__ bhist)
{
    __shared__ int cnt[NBUCK];
    const int tid = threadIdx.x;
    const long long e0 = (long long)blockIdx.x * CH;
    cnt[tid] = 0;
    __syncthreads();
    #pragma unroll
    for (int j = 0; j < EPT; ++j) {
        long long e = e0 + tid + j * 256;
        if (e < E2C) {
            int dd = (e < EE) ? ei[EE + e] : (int)(e - EE);
            atomicAdd(&cnt[dd / BW], 1);
        }
    }
    __syncthreads();
    if (cnt[tid]) atomicAdd(&bhist[tid], cnt[tid]);
}

__global__ void scan_buckets(const int* __restrict__ bhist,
                             int* __restrict__ bbase, int* __restrict__ bcursor,
                             int* __restrict__ rowptr)
{
    __shared__ int tmp[NBUCK];
    const int tid = threadIdx.x;         // <<<1, 256>>>
    int v = bhist[tid];
    tmp[tid] = v;
    __syncthreads();
    for (int off = 1; off < NBUCK; off <<= 1) {
        int t = (tid >= off) ? tmp[tid - off] : 0;
        __syncthreads();
        tmp[tid] += t;
        __syncthreads();
    }
    int excl = tmp[tid] - v;
    bbase[tid]   = excl;
    bcursor[tid] = excl;
    if (tid == NBUCK - 1) bbase[NBUCK] = tmp[tid];   // == E2C
    if (tid == 0) rowptr[NN] = E2C;
}

// bin edges into bucket-grouped pairs with LDS staging (dense global writes)
__global__ __launch_bounds__(256) void bucket_bin(
    const int* __restrict__ ei, int* __restrict__ bcursor, uint2* __restrict__ pairs)
{
    __shared__ int cnt[NBUCK];
    __shared__ int scanex[NBUCK];
    __shared__ int base[NBUCK];
    __shared__ int cur[NBUCK];
    __shared__ uint2 stage[CH];

    const int tid = threadIdx.x;
    const long long e0 = (long long)blockIdx.x * CH;
    cnt[tid] = 0;
    __syncthreads();

    int s[EPT], d[EPT], bk[EPT];
    #pragma unroll
    for (int j = 0; j < EPT; ++j) {
        long long e = e0 + tid + j * 256;
        bool valid = e < E2C;
        int ss = 0, dd = 0;
        if (valid) {
            if (e < EE) { ss = ei[e]; dd = ei[EE + e]; }
            else        { ss = dd = (int)(e - EE); }
        }
        s[j] = ss; d[j] = dd;
        bk[j] = valid ? dd / BW : -1;
        if (valid) atomicAdd(&cnt[bk[j]], 1);
    }
    __syncthreads();

    const int myc = cnt[tid];
    scanex[tid] = myc;
    __syncthreads();
    for (int off = 1; off < NBUCK; off <<= 1) {
        int t = (tid >= off) ? scanex[tid - off] : 0;
        __syncthreads();
        scanex[tid] += t;
        __syncthreads();
    }
    int excl = scanex[tid] - myc;
    __syncthreads();
    scanex[tid] = excl;
    cur[tid]    = excl;
    base[tid]   = atomicAdd(&bcursor[tid], myc);   // reserve global chunk
    __syncthreads();

    #pragma unroll
    for (int j = 0; j < EPT; ++j) {
        if (bk[j] >= 0) {
            int p = atomicAdd(&cur[bk[j]], 1);
            stage[p] = make_uint2((unsigned)s[j], (unsigned)d[j]);
        }
    }
    __syncthreads();

    const int total = (e0 + CH <= E2C) ? CH : (int)(E2C - e0);
    for (int j = tid; j < total; j += 256) {
        uint2 p = stage[j];
        int b = (int)p.y / BW;
        pairs[base[b] + (j - scanex[b])] = p;
    }
}

// one block per bucket: local hist -> local scan -> rowptr + in-window scatter
__global__ __launch_bounds__(256) void bucket_sort(
    const int* __restrict__ bbase, const uint2* __restrict__ pairs,
    int* __restrict__ rowptr, int* __restrict__ sorted_src)
{
    __shared__ int deg[NBUCK];     // per-node degree (BW<=256)
    __shared__ int cur[NBUCK];
    const int b  = blockIdx.x;
    const int n0 = b * BW;
    const int n1 = (n0 + BW < NN) ? n0 + BW : NN;
    const int tid = threadIdx.x;
    const int beg = bbase[b], end = bbase[b + 1];

    deg[tid] = 0;
    __syncthreads();
    for (int i = beg + tid; i < end; i += 256)
        atomicAdd(&deg[(int)pairs[i].y - n0], 1);
    __syncthreads();

    // Hillis-Steele inclusive scan over 256 entries
    int v = deg[tid];
    cur[tid] = v;
    __syncthreads();
    for (int off = 1; off < 256; off <<= 1) {
        int t = (tid >= off) ? cur[tid - off] : 0;
        __syncthreads();
        cur[tid] += t;
        __syncthreads();
    }
    int excl = cur[tid] - v;
    __syncthreads();
    cur[tid] = beg + excl;
    if (n0 + tid < n1) rowptr[n0 + tid] = beg + excl;
    __syncthreads();

    for (int i = beg + tid; i < end; i += 256) {
        uint2 p = pairs[i];
        int pos = atomicAdd(&cur[(int)p.y - n0], 1);
        sorted_src[pos] = (int)p.x;
    }
}

// ---------------------------------------------------------------------------
// Wave-per-node CSR aggregation over bf16 h. 64 lanes = EPN edge groups x
// LCN channel lanes (8 ch each). Zero intra-wave loop divergence; 2-deep
// edge batching; cross-lane reduction folds the EPN partial sums.
// ---------------------------------------------------------------------------
template<int COLS, int NH, bool DO_ELU>
__global__ __launch_bounds__(256) void aggr_node(
    const int* __restrict__ rowptr, const int* __restrict__ sorted_src,
    const unsigned short* __restrict__ hin,
    const float* __restrict__ asrc, const float* __restrict__ adst,
    const float* __restrict__ bias, float* __restrict__ out)
{
    constexpr int LCN = COLS / 8;        // channel lanes per edge (16 or 4)
    constexpr int EPN = 64 / LCN;        // edge-parallel groups (4 or 16)
    constexpr int USTR = COLS / 2;       // uints per h row
    const int lane = threadIdx.x & 63;
    const int lc   = lane & (LCN - 1);   // channel group (consecutive lanes)
    const int eo   = lane / LCN;         // edge offset group
    const int d    = blockIdx.x * 4 + (threadIdx.x >> 6);
    const int cc   = lc * 8;
    const int head = cc / 32;            // 0..NH-1
    const float ad = adst[d * NH + head];
    const int beg = rowptr[d], end = rowptr[d + 1];
    const uint* hp = (const uint*)hin;

    float num[8] = {};
    float den = 0.f;

    auto accum = [&](float w, uint4 H) {
        den += w;
        num[0] = fmaf(w, bflo(H.x), num[0]); num[1] = fmaf(w, bfhi(H.x), num[1]);
        num[2] = fmaf(w, bflo(H.y), num[2]); num[3] = fmaf(w, bfhi(H.y), num[3]);
        num[4] = fmaf(w, bflo(H.z), num[4]); num[5] = fmaf(w, bfhi(H.z), num[5]);
        num[6] = fmaf(w, bflo(H.w), num[6]); num[7] = fmaf(w, bfhi(H.w), num[7]);
    };

    int i = beg;
    for (; i + 2 * EPN <= end; i += 2 * EPN) {
        int sA = sorted_src[i + eo];
        int sB = sorted_src[i + EPN + eo];
        float aA = asrc[sA * NH + head];
        float aB = asrc[sB * NH + head];
        uint4 HA = *(const uint4*)&hp[(long long)sA * USTR + cc / 2];
        uint4 HB = *(const uint4*)&hp[(long long)sB * USTR + cc / 2];
        float lA = aA + ad; lA = lA > 0.f ? lA : 0.2f * lA;
        float lB = aB + ad; lB = lB > 0.f ? lB : 0.2f * lB;
        accum(__builtin_expf(lA), HA);
        accum(__builtin_expf(lB), HB);
    }
    for (i += eo; i < end; i += EPN) {
        int s = sorted_src[i];
        float a = asrc[s * NH + head];
        uint4 H = *(const uint4*)&hp[(long long)s * USTR + cc / 2];
        float l = a + ad; l = l > 0.f ? l : 0.2f * l;
        accum(__builtin_expf(l), H);
    }

    // fold EPN edge groups: xor-shuffle over offsets LCN, 2*LCN, ... 32
    #pragma unroll
    for (int off = LCN; off < 64; off <<= 1) {
        den += __shfl_xor(den, off, 64);
        #pragma unroll
        for (int j = 0; j < 8; ++j)
            num[j] += __shfl_xor(num[j], off, 64);
    }

    if (eo == 0) {
        float inv = 1.f / (den + 1e-16f);
        float v[8];
        #pragma unroll
        for (int j = 0; j < 8; ++j) {
            v[j] = num[j] * inv + bias[cc + j];
            if (DO_ELU) v[j] = v[j] > 0.f ? v[j] : expm1f(v[j]);
        }
        float4 o0 = {v[0], v[1], v[2], v[3]};
        float4 o1 = {v[4], v[5], v[6], v[7]};
        *(float4*)&out[(long long)d * COLS + cc]     = o0;
        *(float4*)&out[(long long)d * COLS + cc + 4] = o1;
    }
}

// ---------------------------------------------------------------------------
extern "C" void kernel_launch(void* const* d_in, const int* in_sizes, int n_in,
                              void* d_out, int out_size, void* d_ws, size_t ws_size,
                              hipStream_t stream)
{
    const float* x   = (const float*)d_in[0];
    const int*   ei  = (const int*)  d_in[1];
    const float* W1  = (const float*)d_in[2];
    const float* as1 = (const float*)d_in[3];
    const float* ad1 = (const float*)d_in[4];
    const float* b1  = (const float*)d_in[5];
    const float* W2  = (const float*)d_in[6];
    const float* as2 = (const float*)d_in[7];
    const float* ad2 = (const float*)d_in[8];
    const float* b2  = (const float*)d_in[9];
    const float* W3  = (const float*)d_in[10];
    const float* as3 = (const float*)d_in[11];
    const float* ad3 = (const float*)d_in[12];
    const float* b3  = (const float*)d_in[13];
    float* out = (float*)d_out;

    // workspace layout
    unsigned short* H = (unsigned short*)d_ws;            // N*128 bf16 (12.8 MB)
    float* O    = (float*)(H + (size_t)NN * 128);         // N*128 f
    float* ASRC = O + (size_t)NN * 128;                   // N*4 f
    float* ADST = ASRC + (size_t)NN * 4;                  // N*4 f
    int* rowptr = (int*)(ADST + (size_t)NN * 4);          // NN+1
    int* sorted = rowptr + (NN + 1);                      // E2C
    int* bhist  = sorted + E2C;                           // NBUCK
    int* bbase  = bhist + NBUCK;                          // NBUCK+1
    int* bcursor= bbase + NBUCK + 1;                      // NBUCK
    // align pairs to 16B
    size_t off = ((size_t)(bcursor + NBUCK) - (size_t)d_ws + 15) & ~(size_t)15;
    uint2* pairs = (uint2*)((char*)d_ws + off);           // E2C uint2 (6.8 MB)

    const int gGemm128 = (NN + 63) / 64;                 // 782
    const int gGemm32  = (NN + 127) / 128;               // 391
    const int gAggr    = (NN + 3) / 4;                   // 12500

    // ---- build CSR (dst-sorted) once; reused by all 3 layers ----
    hipMemsetAsync(bhist, 0, NBUCK * sizeof(int), stream);
    bucket_hist<<<NB_B, 256, 0, stream>>>(ei, bhist);
    scan_buckets<<<1, NBUCK, 0, stream>>>(bhist, bbase, bcursor, rowptr);
    bucket_bin<<<NB_B, 256, 0, stream>>>(ei, bcursor, pairs);
    bucket_sort<<<NBUCK, 256, 0, stream>>>(bbase, pairs, rowptr, sorted);

    // ---- layer 1 (128 -> 4x32 concat, ELU) ----
    gemm_tiled<128, 4, 8><<<gGemm128, 256, 0, stream>>>(x, W1, as1, ad1, H, ASRC, ADST);
    aggr_node<128, 4, true><<<gAggr, 256, 0, stream>>>(rowptr, sorted, H, ASRC, ADST, b1, O);

    // ---- layer 2 (128 -> 4x32 concat, ELU) ----
    gemm_tiled<128, 4, 8><<<gGemm128, 256, 0, stream>>>(O, W2, as2, ad2, H, ASRC, ADST);
    aggr_node<128, 4, true><<<gAggr, 256, 0, stream>>>(rowptr, sorted, H, ASRC, ADST, b2, O);

    // ---- layer 3 (128 -> 32, 1 head, no concat) ----
    gemm_tiled<32, 1, 4><<<gGemm32, 256, 0, stream>>>(O, W3, as3, ad3, H, ASRC, ADST);
    aggr_node<32, 1, false><<<gAggr, 256, 0, stream>>>(rowptr, sorted, H, ASRC, ADST, b3, out);
}